// Round 1
// baseline (910.799 us; speedup 1.0000x reference)
//
#include <hip/hip_runtime.h>
#include <hip/hip_cooperative_groups.h>
#include <math.h>

namespace cg = cooperative_groups;

// Problem constants: B=4, GL=4, GF=128, N=1024, CS=32, CN=16, NA=16, S=512
//
// Flat views (fp32, per b):
//  X  : [512 k][1024 n]
//  U  : [128 c][1024 n] ; P2 view: [1024 m][128 q], q=k*32+i, scale sc[l], l=m>>8
//  S  : [1024 m][512 ju]  (UNsquashed; MS holds squash scales)   ju=j*32+u
//  MS : [1024 m][32 u]    squash scale per (m,u)
//  UH : [8192]            u_hat for aspect routing, e = i*512 + j*32 + u

static constexpr int OFF_U  = 0;          // 524288
static constexpr int OFF_S  = 524288;     // 2097152 (also Upart[4][524288])
static constexpr int OFF_SS = 2621440;    // 16
static constexpr int OFF_BG = 2621456;    // 2048
static constexpr int OFF_G  = 2623504;    // 2048
static constexpr int OFF_VA = 2625552;    // 2048
static constexpr int OFF_MS = 2627600;    // 131072
static constexpr int OFF_UH = 2758672;    // 32768

// ===========================================================================
// MEGA COOPERATIVE KERNEL: the whole pipeline in ONE launch.
// 512 blocks x 256 threads. LDS 51456 B -> 2 blocks/CU co-resident (512 fit).
// Phase bodies are verbatim ports of the proven kernels; only blockIdx maps
// change. 12 grid.sync()s replace 12 dispatch boundaries.
// ===========================================================================
__global__ __launch_bounds__(256, 2) void k_mega(
    const float* __restrict__ X, const float* __restrict__ Wp,
    const float* __restrict__ bp, const float* __restrict__ Wg,
    const float* __restrict__ Wa, const float* __restrict__ Ws,
    float* __restrict__ ws, float* __restrict__ out)
{
    cg::grid_group grid = cg::this_grid();
    __shared__ float sh[12864];            // max over phases: tbu = 12864 floats
    const int bid = blockIdx.x;
    const int t = threadIdx.x;

    float* const U  = ws + OFF_U;
    float* const S  = ws + OFF_S;          // Upart[4] alias before P1
    float* const SS = ws + OFF_SS;
    float* const Bg = ws + OFF_BG;
    float* const G  = ws + OFF_G;
    float* const VA = ws + OFF_VA;
    float* const MS = ws + OFF_MS;
    float* const UH = ws + OFF_UH;

    // ---- P0: primary-capsule partial GEMM (Upart into S region) + zero accums
    {
        float* const Wt = sh;                      // [128][68]
        const int ct = bid & 1, nt = (bid >> 1) & 15;
        const int b = bid >> 7, ks = (bid >> 5) & 3;
        const int tn = t & 15, tc = t >> 4;
        const int c0 = ct * 64, n0 = nt * 64;
#pragma unroll
        for (int i = 0; i < 8; ++i) {
            const int idx = t + i * 256;
            const int c = idx >> 5, k4 = idx & 31;
            const float4 wv = *(const float4*)&Wp[(size_t)(c0 + c) * 512 + ks * 128 + k4 * 4];
            Wt[(k4 * 4 + 0) * 68 + c] = wv.x;
            Wt[(k4 * 4 + 1) * 68 + c] = wv.y;
            Wt[(k4 * 4 + 2) * 68 + c] = wv.z;
            Wt[(k4 * 4 + 3) * 68 + c] = wv.w;
        }
        if (bid == 0)
            for (int i = t; i < 4112; i += 256) SS[i] = 0.f;   // SS+Bg+G contiguous
        __syncthreads();
        float acc[4][4] = {};
        const float* Xp = X + (size_t)b * 524288 + (size_t)(ks * 128) * 1024 + n0 + tn * 4;
#pragma unroll 4
        for (int k = 0; k < 128; ++k) {
            const float4 xv = *(const float4*)(Xp + (size_t)k * 1024);
            const float4 wv = *(const float4*)&Wt[k * 68 + tc * 4];
            const float w[4] = {wv.x, wv.y, wv.z, wv.w};
            const float x[4] = {xv.x, xv.y, xv.z, xv.w};
#pragma unroll
            for (int ci = 0; ci < 4; ++ci)
#pragma unroll
                for (int ni = 0; ni < 4; ++ni)
                    acc[ci][ni] = fmaf(w[ci], x[ni], acc[ci][ni]);
        }
        float* up = S + (size_t)ks * 524288 + (size_t)b * 131072;
#pragma unroll
        for (int ci = 0; ci < 4; ++ci)
            *(float4*)&up[(size_t)(c0 + tc * 4 + ci) * 1024 + n0 + tn * 4] =
                make_float4(acc[ci][0], acc[ci][1], acc[ci][2], acc[ci][3]);
    }
    grid.sync();

    // ---- P1: U = sum_ks Upart + bias; SS[b][l] (512 blocks x 1 channel)
    {
        const int b = bid >> 7, c = bid & 127;
        const int f4 = b * 32768 + c * 256 + t;
        const float4* Up4 = (const float4*)S;
        float4 s = Up4[f4];
#pragma unroll
        for (int ks = 1; ks < 4; ++ks) {
            const float4 p = Up4[ks * 131072 + f4];
            s.x += p.x; s.y += p.y; s.z += p.z; s.w += p.w;
        }
        const float bv = bp[c];
        s.x += bv; s.y += bv; s.z += bv; s.w += bv;
        float ssq = 0.f;
        ssq = fmaf(s.x, s.x, ssq); ssq = fmaf(s.y, s.y, ssq);
        ssq = fmaf(s.z, s.z, ssq); ssq = fmaf(s.w, s.w, ssq);
        ((float4*)U)[f4] = s;
#pragma unroll
        for (int off = 32; off > 0; off >>= 1) ssq += __shfl_down(ssq, off);
        if ((t & 63) == 0) sh[t >> 6] = ssq;
        __syncthreads();
        if (t == 0) atomicAdd(&SS[b * 4 + (c >> 5)], sh[0] + sh[1] + sh[2] + sh[3]);
    }
    grid.sync();

    // ---- routing iterations
    for (int it = 0; it < 3; ++it) {
        // ---- P2: S = (P2*sc) @ (cls o Wg)   (verbatim k_smatmul)
        {
            float* const Pt  = sh;             // [64][65]
            float* const Ct  = sh + 4160;      // [64][65]
            float* const cls = sh + 8320;      // [512]
            const int mt = bid & 15, jt = (bid >> 4) & 7, b = bid >> 7;
            const int tj = t & 15, tm = t >> 4;
            if (t < 32) {
                float vals[16];
                float mx = -1e30f;
                for (int j = 0; j < 16; ++j) { vals[j] = Bg[b * 512 + t * 16 + j]; mx = fmaxf(mx, vals[j]); }
                float sum = 0.f;
                for (int j = 0; j < 16; ++j) { vals[j] = expf(vals[j] - mx); sum += vals[j]; }
                const float inv = 1.f / sum;
                for (int j = 0; j < 16; ++j) cls[t * 16 + j] = vals[j] * inv;
            }
            const float ss = SS[b * 4 + (mt >> 2)];
            const float sc = sqrtf(ss) / (1.f + ss);
            float acc[4][4] = {};
            const float* Ub = U + (size_t)b * 131072 + (size_t)mt * 64 * 128;
            __syncthreads();
            for (int kc = 0; kc < 2; ++kc) {
                for (int x = t; x < 64 * 64; x += 256) {
                    const int r = x >> 6, cq = x & 63;
                    Pt[r * 65 + cq] = Ub[r * 128 + kc * 64 + cq] * sc;
                    const int q = kc * 64 + cq;
                    const int i = q & 31, kk = q >> 5;
                    const int ju = jt * 64 + r;
                    const int j = ju >> 5, u = ju & 31;
                    Ct[r * 65 + cq] = cls[i * 16 + j] * Wg[((i * 16 + j) * 32 + u) * 4 + kk];
                }
                __syncthreads();
                for (int q = 0; q < 64; ++q) {
                    float pv[4], cv[4];
#pragma unroll
                    for (int mm = 0; mm < 4; ++mm) pv[mm] = Pt[(tm * 4 + mm) * 65 + q];
#pragma unroll
                    for (int jj = 0; jj < 4; ++jj) cv[jj] = Ct[(tj * 4 + jj) * 65 + q];
#pragma unroll
                    for (int mm = 0; mm < 4; ++mm)
#pragma unroll
                        for (int jj = 0; jj < 4; ++jj)
                            acc[mm][jj] = fmaf(pv[mm], cv[jj], acc[mm][jj]);
                }
                __syncthreads();
            }
#pragma unroll
            for (int mm = 0; mm < 4; ++mm)
                *(float4*)(S + (size_t)b * 524288 + (size_t)(mt * 64 + tm * 4 + mm) * 512
                             + jt * 64 + tj * 4) =
                    make_float4(acc[mm][0], acc[mm][1], acc[mm][2], acc[mm][3]);
        }
        grid.sync();

        if (it < 2) {
            // ---- P3: MS (verbatim k_mag)
            {
                const int u = t & 31, ml = t >> 5;
                const int b = bid >> 7;
                const int m = (bid & 127) * 8 + ml;
                const float* row = S + (size_t)b * 524288 + (size_t)m * 512;
                float mag = 0.f;
#pragma unroll
                for (int j = 0; j < 16; ++j) { const float v = row[j * 32 + u]; mag = fmaf(v, v, mag); }
                MS[b * 32768 + m * 32 + u] = sqrtf(mag) / (1.f + mag);
            }
            grid.sync();

            // ---- P4: b-update (verbatim k_tbu)
            {
                float* const Ps  = sh;             // [64][132]
                float* const Vs  = sh + 8448;      // [64][68]
                float* const bup = sh + 12800;     // [64]
                const int jt = bid & 7, mc = (bid >> 3) & 15, b = bid >> 7;
                const int tq = t & 31, tjv = t >> 5;
                const int m0 = mc * 64;
                if (t < 64) bup[t] = 0.f;
                const float ss = SS[b * 4 + (mc >> 2)];
                const float sc = sqrtf(ss) / (1.f + ss);
#pragma unroll
                for (int i = 0; i < 8; ++i) {
                    const int f4 = t + i * 256;
                    const int r = f4 >> 5, q4 = f4 & 31;
                    float4 v = *(const float4*)&U[(size_t)b * 131072 + (size_t)(m0 + r) * 128 + q4 * 4];
                    v.x *= sc; v.y *= sc; v.z *= sc; v.w *= sc;
                    *(float4*)&Ps[r * 132 + q4 * 4] = v;
                }
#pragma unroll
                for (int i = 0; i < 4; ++i) {
                    const int f4 = t + i * 256;
                    const int r = f4 >> 4, c4 = f4 & 15;
                    const int m = m0 + r;
                    float4 v = *(const float4*)&S[(size_t)b * 524288 + (size_t)m * 512 + jt * 64 + c4 * 4];
                    const int ub = (c4 * 4) & 31;
                    const float* msp = MS + b * 32768 + m * 32;
                    v.x *= msp[ub + 0]; v.y *= msp[ub + 1]; v.z *= msp[ub + 2]; v.w *= msp[ub + 3];
                    *(float4*)&Vs[r * 68 + c4 * 4] = v;
                }
                __syncthreads();
                float acc[4][8] = {};
#pragma unroll 2
                for (int m = 0; m < 64; ++m) {
                    const float4 p4 = *(const float4*)&Ps[m * 132 + tq * 4];
                    const float4 va = *(const float4*)&Vs[m * 68 + tjv * 8];
                    const float4 vb = *(const float4*)&Vs[m * 68 + tjv * 8 + 4];
                    const float pv[4] = {p4.x, p4.y, p4.z, p4.w};
                    const float vv[8] = {va.x, va.y, va.z, va.w, vb.x, vb.y, vb.z, vb.w};
#pragma unroll
                    for (int qi = 0; qi < 4; ++qi)
#pragma unroll
                        for (int ji = 0; ji < 8; ++ji)
                            acc[qi][ji] = fmaf(pv[qi], vv[ji], acc[qi][ji]);
                }
                const int k = tq >> 3;
                const int j_loc = tjv >> 2;
                const int j = jt * 2 + j_loc;
                const int u0 = (tjv & 3) * 8;
#pragma unroll
                for (int qi = 0; qi < 4; ++qi) {
                    const int i = (tq & 7) * 4 + qi;
                    const float* wp = Wg + ((i * 16 + j) * 32) * 4 + k;
                    float s = 0.f;
#pragma unroll
                    for (int ji = 0; ji < 8; ++ji)
                        s = fmaf(wp[(u0 + ji) * 4], acc[qi][ji], s);
                    s += __shfl_xor(s, 8);
                    s += __shfl_xor(s, 16);
                    s += __shfl_xor(s, 32);
                    if ((t & 56) == 0) atomicAdd(&bup[i * 2 + j_loc], s);
                }
                __syncthreads();
                if (t < 64) {
                    const int ii = t >> 1, jl = t & 1;
                    atomicAdd(&Bg[b * 512 + ii * 16 + jt * 2 + jl], bup[t] * (1.f / 1024.f));
                }
            }
            grid.sync();
        }
    }

    // ---- P5: G = mean_m squash(S)  (verbatim k_maggmean; 128 active blocks)
    if (bid < 128) {
        float* const gacc = sh;                    // [512]
        gacc[t] = 0.f; gacc[t + 256] = 0.f;
        const int u = t & 31, mlg = t >> 5;
        const int b = bid >> 5;
        const int m0 = (bid & 31) * 32 + mlg * 4;
        float preg[16];
#pragma unroll
        for (int j = 0; j < 16; ++j) preg[j] = 0.f;
        __syncthreads();
#pragma unroll
        for (int mi = 0; mi < 4; ++mi) {
            const float* row = S + (size_t)b * 524288 + (size_t)(m0 + mi) * 512;
            float sv[16];
            float mag = 0.f;
#pragma unroll
            for (int j = 0; j < 16; ++j) { sv[j] = row[j * 32 + u]; mag = fmaf(sv[j], sv[j], mag); }
            const float msc = sqrtf(mag) / (1.f + mag);
#pragma unroll
            for (int j = 0; j < 16; ++j) preg[j] = fmaf(sv[j], msc, preg[j]);
        }
#pragma unroll
        for (int j = 0; j < 16; ++j) atomicAdd(&gacc[j * 32 + u], preg[j]);
        __syncthreads();
        atomicAdd(&G[b * 512 + t], gacc[t] * (1.f / 1024.f));
        atomicAdd(&G[b * 512 + 256 + t], gacc[t + 256] * (1.f / 1024.f));
    }
    grid.sync();

    // ---- P6: attention + aspect u_hat (verbatim k_uhat; 32 active blocks)
    if (bid < 32) {
        const int slice = bid & 7, b = bid >> 3;
        float* const g     = sh;                   // 512
        float* const cond  = sh + 512;             // 512
        float* const score = sh + 1024;            // 16
        float* const red   = sh + 1040;            // 16
        g[t] = G[b * 512 + t];
        g[t + 256] = G[b * 512 + 256 + t];
        __syncthreads();
        if (t < 16) {
            float s = 0.f;
            for (int u = 0; u < 32; ++u) s = fmaf(g[t * 32 + u], Wa[u], s);
            red[t] = s;
        }
        __syncthreads();
        if (t == 0) {
            float mx = -1e30f;
            for (int j = 0; j < 16; ++j) mx = fmaxf(mx, red[j]);
            float sum = 0.f;
            for (int j = 0; j < 16; ++j) { score[j] = expf(red[j] - mx); sum += score[j]; }
            const float inv = 1.f / sum;
            for (int j = 0; j < 16; ++j) score[j] *= inv;
        }
        __syncthreads();
        cond[t] = g[t] * score[t >> 5];
        cond[t + 256] = g[t + 256] * score[(t + 256) >> 5];
        __syncthreads();
        const int e0 = slice * 1024 + t * 4;
        const int i = e0 >> 9;
        const float* cp = cond + i * 32;
        const float* wp = Ws + (size_t)e0 * 32;
        float res[4];
#pragma unroll
        for (int jj = 0; jj < 4; ++jj) {
            float s = 0.f;
#pragma unroll
            for (int k8 = 0; k8 < 8; ++k8) {
                const float4 w = *(const float4*)(wp + jj * 32 + k8 * 4);
                s = fmaf(w.x, cp[k8 * 4 + 0], s);
                s = fmaf(w.y, cp[k8 * 4 + 1], s);
                s = fmaf(w.z, cp[k8 * 4 + 2], s);
                s = fmaf(w.w, cp[k8 * 4 + 3], s);
            }
            res[jj] = s;
        }
        ((float4*)UH)[(b * 8192 + e0) >> 2] = make_float4(res[0], res[1], res[2], res[3]);
    }
    grid.sync();

    // ---- P7: 3-iter aspect routing (verbatim k_route; 4 active blocks)
    if (bid < 4) {
        const int b = bid;
        float* const uh   = sh;                    // 8192
        float* const ba   = sh + 8192;             // 256
        float* const cc   = sh + 8448;             // 256
        float* const sbuf = sh + 8704;             // 512
        float* const msc  = sh + 9216;             // 32
#pragma unroll
        for (int i = 0; i < 8; ++i)
            ((float4*)uh)[i * 256 + t] = ((const float4*)UH)[b * 2048 + i * 256 + t];
        ba[t] = 0.f;
        __syncthreads();
        for (int itr = 0; itr < 3; ++itr) {
            if (t < 16) {
                float mx = -1e30f;
                for (int j = 0; j < 16; ++j) mx = fmaxf(mx, ba[t * 16 + j]);
                float sum = 0.f;
                for (int j = 0; j < 16; ++j) { cc[t * 16 + j] = expf(ba[t * 16 + j] - mx); sum += cc[t * 16 + j]; }
                const float inv = 1.f / sum;
                for (int j = 0; j < 16; ++j) cc[t * 16 + j] *= inv;
            }
            __syncthreads();
            for (int h = 0; h < 2; ++h) {
                const int e = h * 256 + t;
                const int j = e >> 5;
                float s = 0.f;
                for (int i = 0; i < 16; ++i) s = fmaf(cc[i * 16 + j], uh[i * 512 + e], s);
                sbuf[e] = s;
            }
            __syncthreads();
            if (t < 32) {
                float mg = 0.f;
                for (int j = 0; j < 16; ++j) { const float x = sbuf[j * 32 + t]; mg = fmaf(x, x, mg); }
                msc[t] = sqrtf(mg) / (1.f + mg);
            }
            __syncthreads();
            for (int h = 0; h < 2; ++h) {
                const int e = h * 256 + t;
                sbuf[e] *= msc[e & 31];
            }
            __syncthreads();
            if (itr < 2) {
                const int i = t >> 4, j = t & 15;
                float s = 0.f;
                for (int u = 0; u < 32; ++u) s = fmaf(uh[i * 512 + j * 32 + u], sbuf[j * 32 + u], s);
                ba[t] += s;
                __syncthreads();
            }
        }
        VA[b * 512 + t] = sbuf[t];
        VA[b * 512 + 256 + t] = sbuf[256 + t];
    }
    grid.sync();

    // ---- P8: broadcast VA to all 512 rows per example (all 512 blocks)
#pragma unroll
    for (int h = 0; h < 2; ++h) {
        const int idx = bid * 512 + h * 256 + t;
        const int b = idx >> 16, jv4 = idx & 127;
        ((float4*)out)[idx] = ((const float4*)VA)[b * 128 + jv4];
    }
}

// ===========================================================================
// FALLBACK PATH: original 13-dispatch pipeline (used only if cooperative
// launch is rejected, e.g. unsupported under graph capture).
// ===========================================================================
__global__ void k_primary_part(const float* __restrict__ X, const float* __restrict__ Wp,
                               float* __restrict__ Upart)
{
    __shared__ float Wt[128 * 68];
    const int ct = blockIdx.x, nt = blockIdx.y;
    const int b = blockIdx.z >> 2, ks = blockIdx.z & 3;
    const int t = threadIdx.x;
    const int tn = t & 15, tc = t >> 4;
    const int c0 = ct * 64, n0 = nt * 64;
#pragma unroll
    for (int i = 0; i < 8; ++i) {
        const int idx = t + i * 256;
        const int c = idx >> 5, k4 = idx & 31;
        const float4 wv = *(const float4*)&Wp[(size_t)(c0 + c) * 512 + ks * 128 + k4 * 4];
        Wt[(k4 * 4 + 0) * 68 + c] = wv.x;
        Wt[(k4 * 4 + 1) * 68 + c] = wv.y;
        Wt[(k4 * 4 + 2) * 68 + c] = wv.z;
        Wt[(k4 * 4 + 3) * 68 + c] = wv.w;
    }
    __syncthreads();
    float acc[4][4] = {};
    const float* Xp = X + (size_t)b * 524288 + (size_t)(ks * 128) * 1024 + n0 + tn * 4;
#pragma unroll 4
    for (int k = 0; k < 128; ++k) {
        const float4 xv = *(const float4*)(Xp + (size_t)k * 1024);
        const float4 wv = *(const float4*)&Wt[k * 68 + tc * 4];
        const float w[4] = {wv.x, wv.y, wv.z, wv.w};
        const float x[4] = {xv.x, xv.y, xv.z, xv.w};
#pragma unroll
        for (int ci = 0; ci < 4; ++ci)
#pragma unroll
            for (int ni = 0; ni < 4; ++ni)
                acc[ci][ni] = fmaf(w[ci], x[ni], acc[ci][ni]);
    }
    float* up = Upart + (size_t)ks * 524288 + (size_t)b * 131072;
#pragma unroll
    for (int ci = 0; ci < 4; ++ci)
        *(float4*)&up[(size_t)(c0 + tc * 4 + ci) * 1024 + n0 + tn * 4] =
            make_float4(acc[ci][0], acc[ci][1], acc[ci][2], acc[ci][3]);
}

__global__ void k_reduceU(const float* __restrict__ Upart, const float* __restrict__ bp,
                          float* __restrict__ U, float* __restrict__ SS)
{
    __shared__ float red[256];
    const int blk = blockIdx.x, t = threadIdx.x;
    const int b = blk >> 5, cg = blk & 31;
    float ssq = 0.f;
#pragma unroll
    for (int i = 0; i < 4; ++i) {
        const int c = cg * 4 + i;
        const int f4 = b * 32768 + c * 256 + t;
        float4 s = ((const float4*)Upart)[f4];
#pragma unroll
        for (int ks = 1; ks < 4; ++ks) {
            const float4 p = ((const float4*)Upart)[ks * 131072 + f4];
            s.x += p.x; s.y += p.y; s.z += p.z; s.w += p.w;
        }
        const float bv = bp[c];
        s.x += bv; s.y += bv; s.z += bv; s.w += bv;
        ssq = fmaf(s.x, s.x, ssq); ssq = fmaf(s.y, s.y, ssq);
        ssq = fmaf(s.z, s.z, ssq); ssq = fmaf(s.w, s.w, ssq);
        ((float4*)U)[f4] = s;
    }
    red[t] = ssq;
    __syncthreads();
    for (int s = 128; s > 0; s >>= 1) {
        if (t < s) red[t] += red[t + s];
        __syncthreads();
    }
    if (t == 0) atomicAdd(&SS[b * 4 + (cg >> 3)], red[0]);
}

__global__ void k_smatmul(const float* __restrict__ U, const float* __restrict__ SS,
                          const float* __restrict__ Bg, const float* __restrict__ Wg,
                          float* __restrict__ S)
{
    __shared__ float Pt[64 * 65];
    __shared__ float Ct[64 * 65];
    __shared__ float cls[512];
    const int mt = blockIdx.x, jt = blockIdx.y, b = blockIdx.z;
    const int t = threadIdx.x;
    const int tj = t & 15, tm = t >> 4;
    if (t < 32) {
        float vals[16];
        float mx = -1e30f;
        for (int j = 0; j < 16; ++j) { vals[j] = Bg[b * 512 + t * 16 + j]; mx = fmaxf(mx, vals[j]); }
        float sum = 0.f;
        for (int j = 0; j < 16; ++j) { vals[j] = expf(vals[j] - mx); sum += vals[j]; }
        const float inv = 1.f / sum;
        for (int j = 0; j < 16; ++j) cls[t * 16 + j] = vals[j] * inv;
    }
    const float ss = SS[b * 4 + (mt >> 2)];
    const float sc = sqrtf(ss) / (1.f + ss);
    float acc[4][4] = {};
    const float* Ub = U + (size_t)b * 131072 + (size_t)mt * 64 * 128;
    __syncthreads();
    for (int kc = 0; kc < 2; ++kc) {
        for (int x = t; x < 64 * 64; x += 256) {
            const int r = x >> 6, cq = x & 63;
            Pt[r * 65 + cq] = Ub[r * 128 + kc * 64 + cq] * sc;
            const int q = kc * 64 + cq;
            const int i = q & 31, kk = q >> 5;
            const int ju = jt * 64 + r;
            const int j = ju >> 5, u = ju & 31;
            Ct[r * 65 + cq] = cls[i * 16 + j] * Wg[((i * 16 + j) * 32 + u) * 4 + kk];
        }
        __syncthreads();
        for (int q = 0; q < 64; ++q) {
            float pv[4], cv[4];
#pragma unroll
            for (int mm = 0; mm < 4; ++mm) pv[mm] = Pt[(tm * 4 + mm) * 65 + q];
#pragma unroll
            for (int jj = 0; jj < 4; ++jj) cv[jj] = Ct[(tj * 4 + jj) * 65 + q];
#pragma unroll
            for (int mm = 0; mm < 4; ++mm)
#pragma unroll
                for (int jj = 0; jj < 4; ++jj)
                    acc[mm][jj] = fmaf(pv[mm], cv[jj], acc[mm][jj]);
        }
        __syncthreads();
    }
#pragma unroll
    for (int mm = 0; mm < 4; ++mm) {
        float4 w = make_float4(acc[mm][0], acc[mm][1], acc[mm][2], acc[mm][3]);
        *(float4*)(S + (size_t)b * 524288 + (size_t)(mt * 64 + tm * 4 + mm) * 512
                     + jt * 64 + tj * 4) = w;
    }
}

__global__ void k_mag(const float* __restrict__ S, float* __restrict__ MS)
{
    const int t = threadIdx.x;
    const int u = t & 31, ml = t >> 5;
    const int m = blockIdx.x * 8 + ml;
    const int b = blockIdx.y;
    const float* row = S + (size_t)b * 524288 + (size_t)m * 512;
    float mag = 0.f;
#pragma unroll
    for (int j = 0; j < 16; ++j) { const float v = row[j * 32 + u]; mag = fmaf(v, v, mag); }
    MS[b * 32768 + m * 32 + u] = sqrtf(mag) / (1.f + mag);
}

__global__ void k_maggmean(const float* __restrict__ S, float* __restrict__ G)
{
    __shared__ float gacc[512];
    const int t = threadIdx.x;
    gacc[t] = 0.f; gacc[t + 256] = 0.f;
    const int u = t & 31, mlg = t >> 5;
    const int b = blockIdx.y;
    const int m0 = blockIdx.x * 32 + mlg * 4;
    float preg[16];
#pragma unroll
    for (int j = 0; j < 16; ++j) preg[j] = 0.f;
    __syncthreads();
#pragma unroll
    for (int mi = 0; mi < 4; ++mi) {
        const float* row = S + (size_t)b * 524288 + (size_t)(m0 + mi) * 512;
        float sv[16];
        float mag = 0.f;
#pragma unroll
        for (int j = 0; j < 16; ++j) { sv[j] = row[j * 32 + u]; mag = fmaf(sv[j], sv[j], mag); }
        const float msc = sqrtf(mag) / (1.f + mag);
#pragma unroll
        for (int j = 0; j < 16; ++j) preg[j] = fmaf(sv[j], msc, preg[j]);
    }
#pragma unroll
    for (int j = 0; j < 16; ++j) atomicAdd(&gacc[j * 32 + u], preg[j]);
    __syncthreads();
    atomicAdd(&G[b * 512 + t], gacc[t] * (1.f / 1024.f));
    atomicAdd(&G[b * 512 + 256 + t], gacc[t + 256] * (1.f / 1024.f));
}

__global__ void k_tbu(const float* __restrict__ U, const float* __restrict__ SS,
                      const float* __restrict__ S, const float* __restrict__ MS,
                      const float* __restrict__ Wg, float* __restrict__ Bg)
{
    __shared__ float Ps[64 * 132];
    __shared__ float Vs[64 * 68];
    __shared__ float bup[64];
    const int jt = blockIdx.x, mc = blockIdx.y, b = blockIdx.z;
    const int t = threadIdx.x;
    const int tq = t & 31, tjv = t >> 5;
    const int m0 = mc * 64;
    if (t < 64) bup[t] = 0.f;
    const float ss = SS[b * 4 + (mc >> 2)];
    const float sc = sqrtf(ss) / (1.f + ss);
#pragma unroll
    for (int i = 0; i < 8; ++i) {
        const int f4 = t + i * 256;
        const int r = f4 >> 5, q4 = f4 & 31;
        float4 v = *(const float4*)&U[(size_t)b * 131072 + (size_t)(m0 + r) * 128 + q4 * 4];
        v.x *= sc; v.y *= sc; v.z *= sc; v.w *= sc;
        *(float4*)&Ps[r * 132 + q4 * 4] = v;
    }
#pragma unroll
    for (int i = 0; i < 4; ++i) {
        const int f4 = t + i * 256;
        const int r = f4 >> 4, c4 = f4 & 15;
        const int m = m0 + r;
        float4 v = *(const float4*)&S[(size_t)b * 524288 + (size_t)m * 512 + jt * 64 + c4 * 4];
        const int ub = (c4 * 4) & 31;
        const float* msp = MS + b * 32768 + m * 32;
        v.x *= msp[ub + 0]; v.y *= msp[ub + 1]; v.z *= msp[ub + 2]; v.w *= msp[ub + 3];
        *(float4*)&Vs[r * 68 + c4 * 4] = v;
    }
    __syncthreads();
    float acc[4][8] = {};
#pragma unroll 2
    for (int m = 0; m < 64; ++m) {
        const float4 p4 = *(const float4*)&Ps[m * 132 + tq * 4];
        const float4 va = *(const float4*)&Vs[m * 68 + tjv * 8];
        const float4 vb = *(const float4*)&Vs[m * 68 + tjv * 8 + 4];
        const float pv[4] = {p4.x, p4.y, p4.z, p4.w};
        const float vv[8] = {va.x, va.y, va.z, va.w, vb.x, vb.y, vb.z, vb.w};
#pragma unroll
        for (int qi = 0; qi < 4; ++qi)
#pragma unroll
            for (int ji = 0; ji < 8; ++ji)
                acc[qi][ji] = fmaf(pv[qi], vv[ji], acc[qi][ji]);
    }
    const int k = tq >> 3;
    const int j_loc = tjv >> 2;
    const int j = jt * 2 + j_loc;
    const int u0 = (tjv & 3) * 8;
#pragma unroll
    for (int qi = 0; qi < 4; ++qi) {
        const int i = (tq & 7) * 4 + qi;
        const float* wp = Wg + ((i * 16 + j) * 32) * 4 + k;
        float s = 0.f;
#pragma unroll
        for (int ji = 0; ji < 8; ++ji)
            s = fmaf(wp[(u0 + ji) * 4], acc[qi][ji], s);
        s += __shfl_xor(s, 8);
        s += __shfl_xor(s, 16);
        s += __shfl_xor(s, 32);
        if ((t & 56) == 0) atomicAdd(&bup[i * 2 + j_loc], s);
    }
    __syncthreads();
    if (t < 64) {
        const int ii = t >> 1, jl = t & 1;
        atomicAdd(&Bg[b * 512 + ii * 16 + jt * 2 + jl], bup[t] * (1.f / 1024.f));
    }
}

__global__ void k_uhat(const float* __restrict__ G, const float* __restrict__ Wa,
                       const float* __restrict__ Ws, float* __restrict__ UH)
{
    const int b = blockIdx.y;
    const int t = threadIdx.x;
    __shared__ float g[512], cond[512], score[16], red[16];
    g[t] = G[b * 512 + t];
    g[t + 256] = G[b * 512 + 256 + t];
    __syncthreads();
    if (t < 16) {
        float s = 0.f;
        for (int u = 0; u < 32; ++u) s = fmaf(g[t * 32 + u], Wa[u], s);
        red[t] = s;
    }
    __syncthreads();
    if (t == 0) {
        float mx = -1e30f;
        for (int j = 0; j < 16; ++j) mx = fmaxf(mx, red[j]);
        float sum = 0.f;
        for (int j = 0; j < 16; ++j) { score[j] = expf(red[j] - mx); sum += score[j]; }
        const float inv = 1.f / sum;
        for (int j = 0; j < 16; ++j) score[j] *= inv;
    }
    __syncthreads();
    cond[t] = g[t] * score[t >> 5];
    cond[t + 256] = g[t + 256] * score[(t + 256) >> 5];
    __syncthreads();
    const int e0 = blockIdx.x * 1024 + t * 4;
    const int i = e0 >> 9;
    const float* cp = cond + i * 32;
    const float* wp = Ws + (size_t)e0 * 32;
    float res[4];
#pragma unroll
    for (int jj = 0; jj < 4; ++jj) {
        float s = 0.f;
#pragma unroll
        for (int k8 = 0; k8 < 8; ++k8) {
            const float4 w = *(const float4*)(wp + jj * 32 + k8 * 4);
            s = fmaf(w.x, cp[k8 * 4 + 0], s);
            s = fmaf(w.y, cp[k8 * 4 + 1], s);
            s = fmaf(w.z, cp[k8 * 4 + 2], s);
            s = fmaf(w.w, cp[k8 * 4 + 3], s);
        }
        res[jj] = s;
    }
    ((float4*)UH)[(b * 8192 + e0) >> 2] = make_float4(res[0], res[1], res[2], res[3]);
}

__global__ void k_route(const float* __restrict__ UH, float* __restrict__ VA)
{
    const int b = blockIdx.x;
    const int t = threadIdx.x;
    __shared__ float uh[8192], ba[256], cc[256], sbuf[512], msc[32];
#pragma unroll
    for (int i = 0; i < 8; ++i)
        ((float4*)uh)[i * 256 + t] = ((const float4*)UH)[b * 2048 + i * 256 + t];
    ba[t] = 0.f;
    __syncthreads();
    for (int it = 0; it < 3; ++it) {
        if (t < 16) {
            float mx = -1e30f;
            for (int j = 0; j < 16; ++j) mx = fmaxf(mx, ba[t * 16 + j]);
            float sum = 0.f;
            for (int j = 0; j < 16; ++j) { cc[t * 16 + j] = expf(ba[t * 16 + j] - mx); sum += cc[t * 16 + j]; }
            const float inv = 1.f / sum;
            for (int j = 0; j < 16; ++j) cc[t * 16 + j] *= inv;
        }
        __syncthreads();
        for (int h = 0; h < 2; ++h) {
            const int e = h * 256 + t;
            const int j = e >> 5;
            float s = 0.f;
            for (int i = 0; i < 16; ++i) s = fmaf(cc[i * 16 + j], uh[i * 512 + e], s);
            sbuf[e] = s;
        }
        __syncthreads();
        if (t < 32) {
            float mg = 0.f;
            for (int j = 0; j < 16; ++j) { const float x = sbuf[j * 32 + t]; mg = fmaf(x, x, mg); }
            msc[t] = sqrtf(mg) / (1.f + mg);
        }
        __syncthreads();
        for (int h = 0; h < 2; ++h) {
            const int e = h * 256 + t;
            sbuf[e] *= msc[e & 31];
        }
        __syncthreads();
        if (it < 2) {
            const int i = t >> 4, j = t & 15;
            float s = 0.f;
            for (int u = 0; u < 32; ++u) s = fmaf(uh[i * 512 + j * 32 + u], sbuf[j * 32 + u], s);
            ba[t] += s;
            __syncthreads();
        }
    }
    VA[b * 512 + t] = sbuf[t];
    VA[b * 512 + 256 + t] = sbuf[256 + t];
}

__global__ void k_out(const float* __restrict__ VA, float* __restrict__ out)
{
    const int idx = blockIdx.x * 256 + threadIdx.x;
    const int b = idx >> 16;
    const int jv4 = idx & 127;
    ((float4*)out)[idx] = ((const float4*)VA)[b * 128 + jv4];
}

// ---------------------------------------------------------------------------
extern "C" void kernel_launch(void* const* d_in, const int* in_sizes, int n_in,
                              void* d_out, int out_size, void* d_ws, size_t ws_size,
                              hipStream_t stream)
{
    const float* X   = (const float*)d_in[0];
    // d_in[1] = hidden — provably unused (softmax shift-invariance kills it)
    const float* Wp  = (const float*)d_in[2];
    const float* bp  = (const float*)d_in[3];
    const float* Wg  = (const float*)d_in[4];
    const float* Wa  = (const float*)d_in[5];
    const float* Wsp = (const float*)d_in[6];
    float* out = (float*)d_out;
    float* ws = (float*)d_ws;

    // ---- preferred path: single cooperative mega-kernel (zeroing in-kernel)
    void* args[8] = {(void*)&X, (void*)&Wp, (void*)&bp, (void*)&Wg,
                     (void*)&Wa, (void*)&Wsp, (void*)&ws, (void*)&out};
    if (hipLaunchCooperativeKernel((const void*)k_mega, dim3(512), dim3(256),
                                   args, 0, stream) == hipSuccess)
        return;

    // ---- fallback: proven 13-dispatch pipeline
    float* U  = ws + OFF_U;
    float* S  = ws + OFF_S;     // also Upart[4] before k_reduceU
    float* SS = ws + OFF_SS;
    float* Bg = ws + OFF_BG;
    float* G  = ws + OFF_G;
    float* VA = ws + OFF_VA;
    float* MS = ws + OFF_MS;
    float* UH = ws + OFF_UH;

    hipMemsetAsync(SS, 0, (16 + 2048 + 2048) * sizeof(float), stream);

    k_primary_part<<<dim3(2, 16, 16), 256, 0, stream>>>(X, Wp, S);
    k_reduceU<<<128, 256, 0, stream>>>(S, bp, U, SS);

    for (int it = 0; it < 3; ++it) {
        k_smatmul<<<dim3(16, 8, 4), 256, 0, stream>>>(U, SS, Bg, Wg, S);
        if (it < 2) {
            k_mag<<<dim3(128, 4), 256, 0, stream>>>(S, MS);
            k_tbu<<<dim3(8, 16, 4), 256, 0, stream>>>(U, SS, S, MS, Wg, Bg);
        } else {
            k_maggmean<<<dim3(32, 4), 256, 0, stream>>>(S, G);
        }
    }

    k_uhat<<<dim3(8, 4), 256, 0, stream>>>(G, Wa, Wsp, UH);
    k_route<<<4, 256, 0, stream>>>(UH, VA);
    k_out<<<1024, 256, 0, stream>>>(VA, out);
}

// Round 2
// 281.069 us; speedup vs baseline: 3.2405x; 3.2405x over previous
//
#include <hip/hip_runtime.h>
#include <math.h>

// Problem constants: B=4, GL=4, GF=128, N=1024, CS=32, CN=16, NA=16, S=512
//
// Flat views (fp32, per b):
//  X   : [512 k][1024 n]
//  U   : [128 c][1024 n] ; P2 view: [1024 m][128 q], q=k*32+i, scale sc[l], l=m>>8
//  S   : [1024 m][512 ju]  (UNsquashed)   ju=j*32+u
//  MSQ : [1024 m][32 u]    SUM OF SQUARES over j per (m,u)  (squash scale derived on the fly)
//
// Workspace layout (floats):
static constexpr int OFF_U    = 0;          // 524288
static constexpr int OFF_S    = 524288;     // 2097152 (also Upart[4][524288])
static constexpr int OFF_SS   = 2621440;    // 16
static constexpr int OFF_BG   = 2621456;    // 2048
static constexpr int OFF_G    = 2623504;    // 2048
static constexpr int OFF_VA   = 2625552;    // 2048
static constexpr int OFF_MSQ0 = 2627600;    // 131072
static constexpr int OFF_MSQ1 = 2758672;    // 131072
// contiguous zero region: SS..MSQ1 end = 16+2048+2048+2048+131072+131072 = 268304 floats

// ---------------------------------------------------------------------------
// K1a: partial U over K-window of 128: Upart[ks] = Wp[:, ks*128:+128] @ X[ks*128:+128, :]
// grid (2 ct, 16 nt, 16 z: b=z>>2, ks=z&3), 256 thr, 4c x 4n outputs each.  [proven]
__global__ void k_primary_part(const float* __restrict__ X, const float* __restrict__ Wp,
                               float* __restrict__ Upart)
{
    __shared__ float Wt[128 * 68];
    const int ct = blockIdx.x, nt = blockIdx.y;
    const int b = blockIdx.z >> 2, ks = blockIdx.z & 3;
    const int t = threadIdx.x;
    const int tn = t & 15, tc = t >> 4;
    const int c0 = ct * 64, n0 = nt * 64;
#pragma unroll
    for (int i = 0; i < 8; ++i) {
        const int idx = t + i * 256;
        const int c = idx >> 5, k4 = idx & 31;
        const float4 wv = *(const float4*)&Wp[(size_t)(c0 + c) * 512 + ks * 128 + k4 * 4];
        Wt[(k4 * 4 + 0) * 68 + c] = wv.x;
        Wt[(k4 * 4 + 1) * 68 + c] = wv.y;
        Wt[(k4 * 4 + 2) * 68 + c] = wv.z;
        Wt[(k4 * 4 + 3) * 68 + c] = wv.w;
    }
    __syncthreads();
    float acc[4][4] = {};
    const float* Xp = X + (size_t)b * 524288 + (size_t)(ks * 128) * 1024 + n0 + tn * 4;
#pragma unroll 4
    for (int k = 0; k < 128; ++k) {
        const float4 xv = *(const float4*)(Xp + (size_t)k * 1024);
        const float4 wv = *(const float4*)&Wt[k * 68 + tc * 4];
        const float w[4] = {wv.x, wv.y, wv.z, wv.w};
        const float x[4] = {xv.x, xv.y, xv.z, xv.w};
#pragma unroll
        for (int ci = 0; ci < 4; ++ci)
#pragma unroll
            for (int ni = 0; ni < 4; ++ni)
                acc[ci][ni] = fmaf(w[ci], x[ni], acc[ci][ni]);
    }
    float* up = Upart + (size_t)ks * 524288 + (size_t)b * 131072;
#pragma unroll
    for (int ci = 0; ci < 4; ++ci)
        *(float4*)&up[(size_t)(c0 + tc * 4 + ci) * 1024 + n0 + tn * 4] =
            make_float4(acc[ci][0], acc[ci][1], acc[ci][2], acc[ci][3]);
}

// ---------------------------------------------------------------------------
// K1b: U = sum_ks Upart[ks] + bp, and SS[b][l] = sum of squares. grid 128.  [proven]
__global__ void k_reduceU(const float* __restrict__ Upart, const float* __restrict__ bp,
                          float* __restrict__ U, float* __restrict__ SS)
{
    __shared__ float red[256];
    const int blk = blockIdx.x, t = threadIdx.x;
    const int b = blk >> 5, cg = blk & 31;
    float ssq = 0.f;
#pragma unroll
    for (int i = 0; i < 4; ++i) {
        const int c = cg * 4 + i;
        const int f4 = b * 32768 + c * 256 + t;
        float4 s = ((const float4*)Upart)[f4];
#pragma unroll
        for (int ks = 1; ks < 4; ++ks) {
            const float4 p = ((const float4*)Upart)[ks * 131072 + f4];
            s.x += p.x; s.y += p.y; s.z += p.z; s.w += p.w;
        }
        const float bv = bp[c];
        s.x += bv; s.y += bv; s.z += bv; s.w += bv;
        ssq = fmaf(s.x, s.x, ssq); ssq = fmaf(s.y, s.y, ssq);
        ssq = fmaf(s.z, s.z, ssq); ssq = fmaf(s.w, s.w, ssq);
        ((float4*)U)[f4] = s;
    }
    red[t] = ssq;
    __syncthreads();
    for (int s = 128; s > 0; s >>= 1) {
        if (t < s) red[t] += red[t + s];
        __syncthreads();
    }
    if (t == 0) atomicAdd(&SS[b * 4 + (cg >> 3)], red[0]);
}

// ---------------------------------------------------------------------------
// K4 v2: S[b][m][ju] = sum_q (U[m][q]*sc) * (cls[i][j]*Wg[i][j][u][k])
// REWRITE: 128m x 64ju tiles, grid (8 mt, 8 jt, 4 b) = 256 blocks, 256 thr,
// 8m x 4j outputs/thread. LDS tiles TRANSPOSED to [q][.] so the inner loop is
// 3x ds_read_b128 + 32 FMA per q (vs 8x ds_read_b32 + 16 FMA before):
// ~1536 wave-LDS-ops/CU (was ~8192) -> LDS-issue time ~7.7us vs ~20us.
// Pt stride 136 floats (16B-aligned b128 reads; tmg*8 offsets hit disjoint
// bank quads -> conflict-free). Ct stride 68 (tjg*4: 2-way max = free).
// Staging writes are lane-stride-1 (conflict-free for any stride).
// Accumulation order over q (0..127 ascending) identical to the old kernel ->
// S is bitwise unchanged.
// Optional epilogue: accumulate MSQ[m][u] = sum_j S^2 (replaces k_mag):
// partner j+32 lives at lane t^8 -> one shfl_xor + global atomicAdd.
__global__ __launch_bounds__(256) void k_smatmul2(
    const float* __restrict__ U, const float* __restrict__ SS,
    const float* __restrict__ Bg, const float* __restrict__ Wg,
    float* __restrict__ S, float* __restrict__ MSQ)
{
    __shared__ float Pt[64 * 136];   // [qL][m 0..127]
    __shared__ float Ct[64 * 68];    // [qL][ju 0..63]
    __shared__ float cls[512];
    const int mt = blockIdx.x, jt = blockIdx.y, b = blockIdx.z;
    const int t = threadIdx.x;
    const int tmg = t >> 4, tjg = t & 15;   // 16 m-groups x 16 j-groups
    const int m0 = mt * 128, j0 = jt * 64;

    if (t < 32) {
        float vals[16];
        float mx = -1e30f;
        for (int j = 0; j < 16; ++j) { vals[j] = Bg[b * 512 + t * 16 + j]; mx = fmaxf(mx, vals[j]); }
        float sum = 0.f;
        for (int j = 0; j < 16; ++j) { vals[j] = expf(vals[j] - mx); sum += vals[j]; }
        const float inv = 1.f / sum;
        for (int j = 0; j < 16; ++j) cls[t * 16 + j] = vals[j] * inv;
    }
    const float ss = SS[b * 4 + (mt >> 1)];          // l = (mt*128)>>8 = mt>>1
    const float sc = sqrtf(ss) / (1.f + ss);
    float acc[8][4] = {};
    const float* Ub = U + (size_t)b * 131072 + (size_t)m0 * 128;
    __syncthreads();

    for (int kc = 0; kc < 2; ++kc) {
        // stage Pt[qL][m]: thread owns row m = t&127, marches qL (stride-1 LDS writes)
        {
            const int m = t & 127;
            const int q0 = t >> 7;                    // 0/1
            const float* up = Ub + (size_t)m * 128 + kc * 64;
#pragma unroll 8
            for (int i = 0; i < 32; ++i) {
                const int qL = q0 + i * 2;
                Pt[qL * 136 + m] = up[qL] * sc;
            }
        }
        // stage Ct[qL][ju]: ju in lanes (stride-1 LDS writes, u-contiguous Wg reads)
#pragma unroll 4
        for (int i = 0; i < 16; ++i) {
            const int x = t + i * 256;
            const int ju = x & 63, qL = x >> 6;
            const int q = kc * 64 + qL;
            const int ii = q & 31, kk = q >> 5;
            const int jv = j0 + ju;
            const int j = jv >> 5, u = jv & 31;
            Ct[qL * 68 + ju] = cls[ii * 16 + j] * Wg[((ii * 16 + j) * 32 + u) * 4 + kk];
        }
        __syncthreads();
#pragma unroll 2
        for (int qL = 0; qL < 64; ++qL) {
            const float4 pa = *(const float4*)&Pt[qL * 136 + tmg * 8];
            const float4 pb = *(const float4*)&Pt[qL * 136 + tmg * 8 + 4];
            const float4 cv = *(const float4*)&Ct[qL * 68 + tjg * 4];
            const float pm[8] = {pa.x, pa.y, pa.z, pa.w, pb.x, pb.y, pb.z, pb.w};
            const float cj[4] = {cv.x, cv.y, cv.z, cv.w};
#pragma unroll
            for (int mm = 0; mm < 8; ++mm)
#pragma unroll
                for (int jj = 0; jj < 4; ++jj)
                    acc[mm][jj] = fmaf(pm[mm], cj[jj], acc[mm][jj]);
        }
        __syncthreads();
    }

#pragma unroll
    for (int mm = 0; mm < 8; ++mm)
        *(float4*)(S + (size_t)b * 524288 + (size_t)(m0 + tmg * 8 + mm) * 512 + j0 + tjg * 4) =
            make_float4(acc[mm][0], acc[mm][1], acc[mm][2], acc[mm][3]);

    if (MSQ) {
        // per (m,u): this thread's jv plus partner's jv+32 (lane t^8, same wave)
#pragma unroll
        for (int mm = 0; mm < 8; ++mm) {
#pragma unroll
            for (int jj = 0; jj < 4; ++jj) {
                float sq = acc[mm][jj] * acc[mm][jj];
                sq += __shfl_xor(sq, 8);
                if ((t & 8) == 0)
                    atomicAdd(&MSQ[b * 32768 + (m0 + tmg * 8 + mm) * 32 + tjg * 4 + jj], sq);
            }
        }
    }
}

// ---------------------------------------------------------------------------
// K6: b-update. Same as proven k_tbu but reads MSQ (sum of squares) and
// derives the squash scale sqrt(q)/(1+q) on the fly (k_mag is gone).
// grid (8 jt, 16 mc, 4 b), 256 thr.
__global__ void k_tbu(const float* __restrict__ U, const float* __restrict__ SS,
                      const float* __restrict__ S, const float* __restrict__ MSQ,
                      const float* __restrict__ Wg, float* __restrict__ Bg)
{
    __shared__ float Ps[64 * 132];   // [m][q], pad 132
    __shared__ float Vs[64 * 68];    // [m][jv], pad 68
    __shared__ float bup[64];        // [i][j_loc]
    const int jt = blockIdx.x, mc = blockIdx.y, b = blockIdx.z;
    const int t = threadIdx.x;
    const int tq = t & 31, tjv = t >> 5;
    const int m0 = mc * 64;
    if (t < 64) bup[t] = 0.f;
    const float ss = SS[b * 4 + (mc >> 2)];
    const float sc = sqrtf(ss) / (1.f + ss);
#pragma unroll
    for (int i = 0; i < 8; ++i) {
        const int f4 = t + i * 256;
        const int r = f4 >> 5, q4 = f4 & 31;
        float4 v = *(const float4*)&U[(size_t)b * 131072 + (size_t)(m0 + r) * 128 + q4 * 4];
        v.x *= sc; v.y *= sc; v.z *= sc; v.w *= sc;
        *(float4*)&Ps[r * 132 + q4 * 4] = v;
    }
#pragma unroll
    for (int i = 0; i < 4; ++i) {
        const int f4 = t + i * 256;
        const int r = f4 >> 4, c4 = f4 & 15;
        const int m = m0 + r;
        float4 v = *(const float4*)&S[(size_t)b * 524288 + (size_t)m * 512 + jt * 64 + c4 * 4];
        const int ub = (c4 * 4) & 31;
        const float* qp = MSQ + b * 32768 + m * 32;
        const float q0 = qp[ub + 0], q1 = qp[ub + 1], q2 = qp[ub + 2], q3 = qp[ub + 3];
        v.x *= sqrtf(q0) / (1.f + q0);
        v.y *= sqrtf(q1) / (1.f + q1);
        v.z *= sqrtf(q2) / (1.f + q2);
        v.w *= sqrtf(q3) / (1.f + q3);
        *(float4*)&Vs[r * 68 + c4 * 4] = v;
    }
    __syncthreads();
    float acc[4][8] = {};
#pragma unroll 2
    for (int m = 0; m < 64; ++m) {
        const float4 p4 = *(const float4*)&Ps[m * 132 + tq * 4];
        const float4 va = *(const float4*)&Vs[m * 68 + tjv * 8];
        const float4 vb = *(const float4*)&Vs[m * 68 + tjv * 8 + 4];
        const float pv[4] = {p4.x, p4.y, p4.z, p4.w};
        const float vv[8] = {va.x, va.y, va.z, va.w, vb.x, vb.y, vb.z, vb.w};
#pragma unroll
        for (int qi = 0; qi < 4; ++qi)
#pragma unroll
            for (int ji = 0; ji < 8; ++ji)
                acc[qi][ji] = fmaf(pv[qi], vv[ji], acc[qi][ji]);
    }
    const int k = tq >> 3;
    const int j_loc = tjv >> 2;
    const int j = jt * 2 + j_loc;
    const int u0 = (tjv & 3) * 8;
#pragma unroll
    for (int qi = 0; qi < 4; ++qi) {
        const int i = (tq & 7) * 4 + qi;
        const float* wp = Wg + ((i * 16 + j) * 32) * 4 + k;
        float s = 0.f;
#pragma unroll
        for (int ji = 0; ji < 8; ++ji)
            s = fmaf(wp[(u0 + ji) * 4], acc[qi][ji], s);
        s += __shfl_xor(s, 8);
        s += __shfl_xor(s, 16);
        s += __shfl_xor(s, 32);
        if ((t & 56) == 0) atomicAdd(&bup[i * 2 + j_loc], s);
    }
    __syncthreads();
    if (t < 64) {
        const int ii = t >> 1, jl = t & 1;
        atomicAdd(&Bg[b * 512 + ii * 16 + jt * 2 + jl], bup[t] * (1.f / 1024.f));
    }
}

// ---------------------------------------------------------------------------
// K5b (last iter): mag + mean fused: G[b][jv] = (1/1024) sum_m S*msc. [proven]
__global__ void k_maggmean(const float* __restrict__ S, float* __restrict__ G)
{
    __shared__ float gacc[512];
    const int t = threadIdx.x;
    gacc[t] = 0.f; gacc[t + 256] = 0.f;
    const int u = t & 31, mlg = t >> 5;
    const int b = blockIdx.y;
    const int m0 = blockIdx.x * 32 + mlg * 4;
    float preg[16];
#pragma unroll
    for (int j = 0; j < 16; ++j) preg[j] = 0.f;
    __syncthreads();
#pragma unroll
    for (int mi = 0; mi < 4; ++mi) {
        const float* row = S + (size_t)b * 524288 + (size_t)(m0 + mi) * 512;
        float sv[16];
        float mag = 0.f;
#pragma unroll
        for (int j = 0; j < 16; ++j) { sv[j] = row[j * 32 + u]; mag = fmaf(sv[j], sv[j], mag); }
        const float msc = sqrtf(mag) / (1.f + mag);
#pragma unroll
        for (int j = 0; j < 16; ++j) preg[j] = fmaf(sv[j], msc, preg[j]);
    }
#pragma unroll
    for (int j = 0; j < 16; ++j) atomicAdd(&gacc[j * 32 + u], preg[j]);
    __syncthreads();
    atomicAdd(&G[b * 512 + t], gacc[t] * (1.f / 1024.f));
    atomicAdd(&G[b * 512 + 256 + t], gacc[t + 256] * (1.f / 1024.f));
}

// ---------------------------------------------------------------------------
// K8: attention + aspect u_hat + 3-iter aspect routing, fused.
// UH stays in LDS (no global round-trip). grid 4 (b), 256 thr.
__global__ void k_routeF(const float* __restrict__ G, const float* __restrict__ Wa,
                         const float* __restrict__ Ws, float* __restrict__ VA)
{
    const int b = blockIdx.x;
    const int t = threadIdx.x;
    __shared__ float uh[8192], g[512], cond[512], score[16], red[16];
    __shared__ float ba[256], cc[256], sbuf[512], msc[32];
    g[t] = G[b * 512 + t];
    g[t + 256] = G[b * 512 + 256 + t];
    ba[t] = 0.f;
    __syncthreads();
    if (t < 16) {
        float s = 0.f;
        for (int u = 0; u < 32; ++u) s = fmaf(g[t * 32 + u], Wa[u], s);
        red[t] = s;
    }
    __syncthreads();
    if (t == 0) {
        float mx = -1e30f;
        for (int j = 0; j < 16; ++j) mx = fmaxf(mx, red[j]);
        float sum = 0.f;
        for (int j = 0; j < 16; ++j) { score[j] = expf(red[j] - mx); sum += score[j]; }
        const float inv = 1.f / sum;
        for (int j = 0; j < 16; ++j) score[j] *= inv;
    }
    __syncthreads();
    cond[t] = g[t] * score[t >> 5];
    cond[t + 256] = g[t + 256] * score[(t + 256) >> 5];
    __syncthreads();
    // u_hat: uh[e] = sum_k Ws[e][k] * cond[i*32+k], e = i*512 + j*32 + u
#pragma unroll
    for (int slice = 0; slice < 8; ++slice) {
        const int e0 = slice * 1024 + t * 4;
        const int i = e0 >> 9;
        const float* cp = cond + i * 32;
        const float* wp = Ws + (size_t)e0 * 32;
        float res[4];
#pragma unroll
        for (int jj = 0; jj < 4; ++jj) {
            float s = 0.f;
#pragma unroll
            for (int k8 = 0; k8 < 8; ++k8) {
                const float4 w = *(const float4*)(wp + jj * 32 + k8 * 4);
                s = fmaf(w.x, cp[k8 * 4 + 0], s);
                s = fmaf(w.y, cp[k8 * 4 + 1], s);
                s = fmaf(w.z, cp[k8 * 4 + 2], s);
                s = fmaf(w.w, cp[k8 * 4 + 3], s);
            }
            res[jj] = s;
        }
        *(float4*)&uh[e0] = make_float4(res[0], res[1], res[2], res[3]);
    }
    __syncthreads();
    // 3-iter routing on LDS-resident uh (verbatim k_route body)
    for (int it = 0; it < 3; ++it) {
        if (t < 16) {
            float mx = -1e30f;
            for (int j = 0; j < 16; ++j) mx = fmaxf(mx, ba[t * 16 + j]);
            float sum = 0.f;
            for (int j = 0; j < 16; ++j) { cc[t * 16 + j] = expf(ba[t * 16 + j] - mx); sum += cc[t * 16 + j]; }
            const float inv = 1.f / sum;
            for (int j = 0; j < 16; ++j) cc[t * 16 + j] *= inv;
        }
        __syncthreads();
        for (int h = 0; h < 2; ++h) {
            const int e = h * 256 + t;
            const int j = e >> 5;
            float s = 0.f;
            for (int i = 0; i < 16; ++i) s = fmaf(cc[i * 16 + j], uh[i * 512 + e], s);
            sbuf[e] = s;
        }
        __syncthreads();
        if (t < 32) {
            float mg = 0.f;
            for (int j = 0; j < 16; ++j) { const float x = sbuf[j * 32 + t]; mg = fmaf(x, x, mg); }
            msc[t] = sqrtf(mg) / (1.f + mg);
        }
        __syncthreads();
        for (int h = 0; h < 2; ++h) {
            const int e = h * 256 + t;
            sbuf[e] *= msc[e & 31];
        }
        __syncthreads();
        if (it < 2) {
            const int i = t >> 4, j = t & 15;
            float s = 0.f;
            for (int u = 0; u < 32; ++u) s = fmaf(uh[i * 512 + j * 32 + u], sbuf[j * 32 + u], s);
            ba[t] += s;
            __syncthreads();
        }
    }
    VA[b * 512 + t] = sbuf[t];
    VA[b * 512 + 256 + t] = sbuf[256 + t];
}

// ---------------------------------------------------------------------------
// K9: broadcast VA to all 512 rows per example  [proven]
__global__ void k_out(const float* __restrict__ VA, float* __restrict__ out)
{
    const int idx = blockIdx.x * 256 + threadIdx.x;
    const int b = idx >> 16;
    const int jv4 = idx & 127;
    ((float4*)out)[idx] = ((const float4*)VA)[b * 128 + jv4];
}

// ---------------------------------------------------------------------------
extern "C" void kernel_launch(void* const* d_in, const int* in_sizes, int n_in,
                              void* d_out, int out_size, void* d_ws, size_t ws_size,
                              hipStream_t stream)
{
    const float* X   = (const float*)d_in[0];
    // d_in[1] = hidden — provably unused (softmax shift-invariance kills it)
    const float* Wp  = (const float*)d_in[2];
    const float* bp  = (const float*)d_in[3];
    const float* Wg  = (const float*)d_in[4];
    const float* Wa  = (const float*)d_in[5];
    const float* Wsp = (const float*)d_in[6];
    float* out = (float*)d_out;
    float* ws = (float*)d_ws;

    float* U    = ws + OFF_U;
    float* S    = ws + OFF_S;     // also Upart[4] before k_reduceU
    float* SS   = ws + OFF_SS;
    float* Bg   = ws + OFF_BG;
    float* G    = ws + OFF_G;
    float* VA   = ws + OFF_VA;
    float* MSQ0 = ws + OFF_MSQ0;
    float* MSQ1 = ws + OFF_MSQ1;

    // zero SS(16)+Bg(2048)+G(2048)+VA(2048)+MSQ0(131072)+MSQ1(131072) — contiguous
    hipMemsetAsync(SS, 0, 268304 * sizeof(float), stream);

    k_primary_part<<<dim3(2, 16, 16), 256, 0, stream>>>(X, Wp, S);
    k_reduceU<<<128, 256, 0, stream>>>(S, bp, U, SS);

    // it 0
    k_smatmul2<<<dim3(8, 8, 4), 256, 0, stream>>>(U, SS, Bg, Wg, S, MSQ0);
    k_tbu<<<dim3(8, 16, 4), 256, 0, stream>>>(U, SS, S, MSQ0, Wg, Bg);
    // it 1
    k_smatmul2<<<dim3(8, 8, 4), 256, 0, stream>>>(U, SS, Bg, Wg, S, MSQ1);
    k_tbu<<<dim3(8, 16, 4), 256, 0, stream>>>(U, SS, S, MSQ1, Wg, Bg);
    // it 2
    k_smatmul2<<<dim3(8, 8, 4), 256, 0, stream>>>(U, SS, Bg, Wg, S, nullptr);
    k_maggmean<<<dim3(32, 4), 256, 0, stream>>>(S, G);

    k_routeF<<<4, 256, 0, stream>>>(G, Wa, Wsp, VA);
    k_out<<<1024, 256, 0, stream>>>(VA, out);
}

// Round 3
// 239.617 us; speedup vs baseline: 3.8011x; 1.1730x over previous
//
#include <hip/hip_runtime.h>
#include <math.h>

// Problem constants: B=4, GL=4, GF=128, N=1024, CS=32, CN=16, NA=16, S=512
//
// Flat views (fp32, per b):
//  X   : [512 k][1024 n]
//  U   : [128 c][1024 n] ; P2 view: [1024 m][128 q], q=k*32+i, scale sc[l], l=m>>8
//  S   : [1024 m][512 ju]  (UNsquashed)   ju=j*32+u
//  MSQ : [1024 m][32 u]    SUM OF SQUARES over j per (m,u); squash scale derived on the fly
//  UH  : [8192]            u_hat for aspect routing, e = i*512 + j*32 + u
//
// Workspace layout (floats):
static constexpr int OFF_U    = 0;          // 524288
static constexpr int OFF_S    = 524288;     // 2097152 (also Upart[4][524288])
static constexpr int OFF_SS   = 2621440;    // 16
static constexpr int OFF_BG   = 2621456;    // 2048
static constexpr int OFF_G    = 2623504;    // 2048
static constexpr int OFF_VA   = 2625552;    // 2048
static constexpr int OFF_MSQ0 = 2627600;    // 131072
static constexpr int OFF_MSQ1 = 2758672;    // 131072
static constexpr int OFF_UH   = 2889744;    // 32768
// contiguous zero region: SS..MSQ1 = 16+2048+2048+2048+131072+131072 = 268304 floats

// ---------------------------------------------------------------------------
// K1a: partial U over K-window of 128: Upart[ks] = Wp[:, ks*128:+128] @ X[ks*128:+128, :]
// grid (2 ct, 16 nt, 16 z: b=z>>2, ks=z&3), 256 thr, 4c x 4n outputs each.  [proven]
__global__ void k_primary_part(const float* __restrict__ X, const float* __restrict__ Wp,
                               float* __restrict__ Upart)
{
    __shared__ float Wt[128 * 68];
    const int ct = blockIdx.x, nt = blockIdx.y;
    const int b = blockIdx.z >> 2, ks = blockIdx.z & 3;
    const int t = threadIdx.x;
    const int tn = t & 15, tc = t >> 4;
    const int c0 = ct * 64, n0 = nt * 64;
#pragma unroll
    for (int i = 0; i < 8; ++i) {
        const int idx = t + i * 256;
        const int c = idx >> 5, k4 = idx & 31;
        const float4 wv = *(const float4*)&Wp[(size_t)(c0 + c) * 512 + ks * 128 + k4 * 4];
        Wt[(k4 * 4 + 0) * 68 + c] = wv.x;
        Wt[(k4 * 4 + 1) * 68 + c] = wv.y;
        Wt[(k4 * 4 + 2) * 68 + c] = wv.z;
        Wt[(k4 * 4 + 3) * 68 + c] = wv.w;
    }
    __syncthreads();
    float acc[4][4] = {};
    const float* Xp = X + (size_t)b * 524288 + (size_t)(ks * 128) * 1024 + n0 + tn * 4;
#pragma unroll 4
    for (int k = 0; k < 128; ++k) {
        const float4 xv = *(const float4*)(Xp + (size_t)k * 1024);
        const float4 wv = *(const float4*)&Wt[k * 68 + tc * 4];
        const float w[4] = {wv.x, wv.y, wv.z, wv.w};
        const float x[4] = {xv.x, xv.y, xv.z, xv.w};
#pragma unroll
        for (int ci = 0; ci < 4; ++ci)
#pragma unroll
            for (int ni = 0; ni < 4; ++ni)
                acc[ci][ni] = fmaf(w[ci], x[ni], acc[ci][ni]);
    }
    float* up = Upart + (size_t)ks * 524288 + (size_t)b * 131072;
#pragma unroll
    for (int ci = 0; ci < 4; ++ci)
        *(float4*)&up[(size_t)(c0 + tc * 4 + ci) * 1024 + n0 + tn * 4] =
            make_float4(acc[ci][0], acc[ci][1], acc[ci][2], acc[ci][3]);
}

// ---------------------------------------------------------------------------
// K1b: U = sum_ks Upart[ks] + bp, and SS[b][l] = sum of squares. grid 128.  [proven]
__global__ void k_reduceU(const float* __restrict__ Upart, const float* __restrict__ bp,
                          float* __restrict__ U, float* __restrict__ SS)
{
    __shared__ float red[256];
    const int blk = blockIdx.x, t = threadIdx.x;
    const int b = blk >> 5, cg = blk & 31;
    float ssq = 0.f;
#pragma unroll
    for (int i = 0; i < 4; ++i) {
        const int c = cg * 4 + i;
        const int f4 = b * 32768 + c * 256 + t;
        float4 s = ((const float4*)Upart)[f4];
#pragma unroll
        for (int ks = 1; ks < 4; ++ks) {
            const float4 p = ((const float4*)Upart)[ks * 131072 + f4];
            s.x += p.x; s.y += p.y; s.z += p.z; s.w += p.w;
        }
        const float bv = bp[c];
        s.x += bv; s.y += bv; s.z += bv; s.w += bv;
        ssq = fmaf(s.x, s.x, ssq); ssq = fmaf(s.y, s.y, ssq);
        ssq = fmaf(s.z, s.z, ssq); ssq = fmaf(s.w, s.w, ssq);
        ((float4*)U)[f4] = s;
    }
    red[t] = ssq;
    __syncthreads();
    for (int s = 128; s > 0; s >>= 1) {
        if (t < s) red[t] += red[t + s];
        __syncthreads();
    }
    if (t == 0) atomicAdd(&SS[b * 4 + (cg >> 3)], red[0]);
}

// ---------------------------------------------------------------------------
// K4: S[b][m][ju] = sum_q (U[m][q]*sc) * (cls[i][j]*Wg[i][j][u][k])
// grid (16 mt, 8 jt, 4 b), 64x64 tiles, K=128 in 2 chunks.  [proven original]
// + MSQ epilogue (replaces k_mag): MSQ[m][u] += acc^2 + partner(j+32)'s acc^2.
// Partner lives at lane t^8 (tj^8, same wave). 8-way global atomic contention
// per (m,u) across jt blocks. Epilogue validated in round 2 (absmax 0.0).
__global__ void k_smatmul(const float* __restrict__ U, const float* __restrict__ SS,
                          const float* __restrict__ Bg, const float* __restrict__ Wg,
                          float* __restrict__ S, float* __restrict__ MSQ)
{
    __shared__ float Pt[64 * 65];
    __shared__ float Ct[64 * 65];
    __shared__ float cls[512];
    const int mt = blockIdx.x, jt = blockIdx.y, b = blockIdx.z;
    const int t = threadIdx.x;
    const int tj = t & 15, tm = t >> 4;
    if (t < 32) {
        float vals[16];
        float mx = -1e30f;
        for (int j = 0; j < 16; ++j) { vals[j] = Bg[b * 512 + t * 16 + j]; mx = fmaxf(mx, vals[j]); }
        float sum = 0.f;
        for (int j = 0; j < 16; ++j) { vals[j] = expf(vals[j] - mx); sum += vals[j]; }
        const float inv = 1.f / sum;
        for (int j = 0; j < 16; ++j) cls[t * 16 + j] = vals[j] * inv;
    }
    const float ss = SS[b * 4 + (mt >> 2)];
    const float sc = sqrtf(ss) / (1.f + ss);
    float acc[4][4] = {};
    const float* Ub = U + (size_t)b * 131072 + (size_t)mt * 64 * 128;
    __syncthreads();
    for (int kc = 0; kc < 2; ++kc) {
        for (int x = t; x < 64 * 64; x += 256) {
            const int r = x >> 6, cq = x & 63;
            Pt[r * 65 + cq] = Ub[r * 128 + kc * 64 + cq] * sc;
            const int q = kc * 64 + cq;
            const int i = q & 31, kk = q >> 5;
            const int ju = jt * 64 + r;
            const int j = ju >> 5, u = ju & 31;
            Ct[r * 65 + cq] = cls[i * 16 + j] * Wg[((i * 16 + j) * 32 + u) * 4 + kk];
        }
        __syncthreads();
        for (int q = 0; q < 64; ++q) {
            float pv[4], cv[4];
#pragma unroll
            for (int mm = 0; mm < 4; ++mm) pv[mm] = Pt[(tm * 4 + mm) * 65 + q];
#pragma unroll
            for (int jj = 0; jj < 4; ++jj) cv[jj] = Ct[(tj * 4 + jj) * 65 + q];
#pragma unroll
            for (int mm = 0; mm < 4; ++mm)
#pragma unroll
                for (int jj = 0; jj < 4; ++jj)
                    acc[mm][jj] = fmaf(pv[mm], cv[jj], acc[mm][jj]);
        }
        __syncthreads();
    }
#pragma unroll
    for (int mm = 0; mm < 4; ++mm) {
        float4 w = make_float4(acc[mm][0], acc[mm][1], acc[mm][2], acc[mm][3]);
        *(float4*)(S + (size_t)b * 524288 + (size_t)(mt * 64 + tm * 4 + mm) * 512
                     + jt * 64 + tj * 4) = w;
    }
    if (MSQ) {
        // this thread: m = mt*64+tm*4+mm, ju = jt*64+tj*4+jj; u = (tj*4+jj)&31.
        // partner with same (m,u), other j: lane t^8 (flips tj bit 3, same wave).
#pragma unroll
        for (int mm = 0; mm < 4; ++mm) {
#pragma unroll
            for (int jj = 0; jj < 4; ++jj) {
                float sq = acc[mm][jj] * acc[mm][jj];
                sq += __shfl_xor(sq, 8);
                if ((t & 8) == 0)
                    atomicAdd(&MSQ[b * 32768 + (mt * 64 + tm * 4 + mm) * 32 + tj * 4 + jj], sq);
            }
        }
    }
}

// ---------------------------------------------------------------------------
// K6: b-update. Proven k_tbu, reading MSQ (sum of squares) and deriving the
// squash scale sqrt(q)/(1+q) on the fly (k_mag eliminated). [validated r2]
// grid (8 jt, 16 mc, 4 b), 256 thr.
__global__ void k_tbu(const float* __restrict__ U, const float* __restrict__ SS,
                      const float* __restrict__ S, const float* __restrict__ MSQ,
                      const float* __restrict__ Wg, float* __restrict__ Bg)
{
    __shared__ float Ps[64 * 132];   // [m][q], pad 132
    __shared__ float Vs[64 * 68];    // [m][jv], pad 68
    __shared__ float bup[64];        // [i][j_loc]
    const int jt = blockIdx.x, mc = blockIdx.y, b = blockIdx.z;
    const int t = threadIdx.x;
    const int tq = t & 31, tjv = t >> 5;
    const int m0 = mc * 64;
    if (t < 64) bup[t] = 0.f;
    const float ss = SS[b * 4 + (mc >> 2)];
    const float sc = sqrtf(ss) / (1.f + ss);
#pragma unroll
    for (int i = 0; i < 8; ++i) {
        const int f4 = t + i * 256;
        const int r = f4 >> 5, q4 = f4 & 31;
        float4 v = *(const float4*)&U[(size_t)b * 131072 + (size_t)(m0 + r) * 128 + q4 * 4];
        v.x *= sc; v.y *= sc; v.z *= sc; v.w *= sc;
        *(float4*)&Ps[r * 132 + q4 * 4] = v;
    }
#pragma unroll
    for (int i = 0; i < 4; ++i) {
        const int f4 = t + i * 256;
        const int r = f4 >> 4, c4 = f4 & 15;
        const int m = m0 + r;
        float4 v = *(const float4*)&S[(size_t)b * 524288 + (size_t)m * 512 + jt * 64 + c4 * 4];
        const int ub = (c4 * 4) & 31;
        const float* qp = MSQ + b * 32768 + m * 32;
        const float q0 = qp[ub + 0], q1 = qp[ub + 1], q2 = qp[ub + 2], q3 = qp[ub + 3];
        v.x *= sqrtf(q0) / (1.f + q0);
        v.y *= sqrtf(q1) / (1.f + q1);
        v.z *= sqrtf(q2) / (1.f + q2);
        v.w *= sqrtf(q3) / (1.f + q3);
        *(float4*)&Vs[r * 68 + c4 * 4] = v;
    }
    __syncthreads();
    float acc[4][8] = {};
#pragma unroll 2
    for (int m = 0; m < 64; ++m) {
        const float4 p4 = *(const float4*)&Ps[m * 132 + tq * 4];
        const float4 va = *(const float4*)&Vs[m * 68 + tjv * 8];
        const float4 vb = *(const float4*)&Vs[m * 68 + tjv * 8 + 4];
        const float pv[4] = {p4.x, p4.y, p4.z, p4.w};
        const float vv[8] = {va.x, va.y, va.z, va.w, vb.x, vb.y, vb.z, vb.w};
#pragma unroll
        for (int qi = 0; qi < 4; ++qi)
#pragma unroll
            for (int ji = 0; ji < 8; ++ji)
                acc[qi][ji] = fmaf(pv[qi], vv[ji], acc[qi][ji]);
    }
    const int k = tq >> 3;
    const int j_loc = tjv >> 2;
    const int j = jt * 2 + j_loc;
    const int u0 = (tjv & 3) * 8;
#pragma unroll
    for (int qi = 0; qi < 4; ++qi) {
        const int i = (tq & 7) * 4 + qi;
        const float* wp = Wg + ((i * 16 + j) * 32) * 4 + k;
        float s = 0.f;
#pragma unroll
        for (int ji = 0; ji < 8; ++ji)
            s = fmaf(wp[(u0 + ji) * 4], acc[qi][ji], s);
        s += __shfl_xor(s, 8);
        s += __shfl_xor(s, 16);
        s += __shfl_xor(s, 32);
        if ((t & 56) == 0) atomicAdd(&bup[i * 2 + j_loc], s);
    }
    __syncthreads();
    if (t < 64) {
        const int ii = t >> 1, jl = t & 1;
        atomicAdd(&Bg[b * 512 + ii * 16 + jt * 2 + jl], bup[t] * (1.f / 1024.f));
    }
}

// ---------------------------------------------------------------------------
// K5b (last iter): mag + mean fused: G[b][jv] = (1/1024) sum_m S*msc. [proven]
__global__ void k_maggmean(const float* __restrict__ S, float* __restrict__ G)
{
    __shared__ float gacc[512];
    const int t = threadIdx.x;
    gacc[t] = 0.f; gacc[t + 256] = 0.f;
    const int u = t & 31, mlg = t >> 5;
    const int b = blockIdx.y;
    const int m0 = blockIdx.x * 32 + mlg * 4;
    float preg[16];
#pragma unroll
    for (int j = 0; j < 16; ++j) preg[j] = 0.f;
    __syncthreads();
#pragma unroll
    for (int mi = 0; mi < 4; ++mi) {
        const float* row = S + (size_t)b * 524288 + (size_t)(m0 + mi) * 512;
        float sv[16];
        float mag = 0.f;
#pragma unroll
        for (int j = 0; j < 16; ++j) { sv[j] = row[j * 32 + u]; mag = fmaf(sv[j], sv[j], mag); }
        const float msc = sqrtf(mag) / (1.f + mag);
#pragma unroll
        for (int j = 0; j < 16; ++j) preg[j] = fmaf(sv[j], msc, preg[j]);
    }
#pragma unroll
    for (int j = 0; j < 16; ++j) atomicAdd(&gacc[j * 32 + u], preg[j]);
    __syncthreads();
    atomicAdd(&G[b * 512 + t], gacc[t] * (1.f / 1024.f));
    atomicAdd(&G[b * 512 + 256 + t], gacc[t + 256] * (1.f / 1024.f));
}

// ---------------------------------------------------------------------------
// K8a: UH[b][e] = sum_k Ws[e][k] * cond[b][i*32+k]. grid (8 slices, 4 b). [proven]
__global__ void k_uhat(const float* __restrict__ G, const float* __restrict__ Wa,
                       const float* __restrict__ Ws, float* __restrict__ UH)
{
    const int b = blockIdx.y;
    const int t = threadIdx.x;
    __shared__ float g[512], cond[512], score[16], red[16];
    g[t] = G[b * 512 + t];
    g[t + 256] = G[b * 512 + 256 + t];
    __syncthreads();
    if (t < 16) {
        float s = 0.f;
        for (int u = 0; u < 32; ++u) s = fmaf(g[t * 32 + u], Wa[u], s);
        red[t] = s;
    }
    __syncthreads();
    if (t == 0) {
        float mx = -1e30f;
        for (int j = 0; j < 16; ++j) mx = fmaxf(mx, red[j]);
        float sum = 0.f;
        for (int j = 0; j < 16; ++j) { score[j] = expf(red[j] - mx); sum += score[j]; }
        const float inv = 1.f / sum;
        for (int j = 0; j < 16; ++j) score[j] *= inv;
    }
    __syncthreads();
    cond[t] = g[t] * score[t >> 5];
    cond[t + 256] = g[t + 256] * score[(t + 256) >> 5];
    __syncthreads();
    const int e0 = blockIdx.x * 1024 + t * 4;
    const int i = e0 >> 9;
    const float* cp = cond + i * 32;
    const float* wp = Ws + (size_t)e0 * 32;
    float res[4];
#pragma unroll
    for (int jj = 0; jj < 4; ++jj) {
        float s = 0.f;
#pragma unroll
        for (int k8 = 0; k8 < 8; ++k8) {
            const float4 w = *(const float4*)(wp + jj * 32 + k8 * 4);
            s = fmaf(w.x, cp[k8 * 4 + 0], s);
            s = fmaf(w.y, cp[k8 * 4 + 1], s);
            s = fmaf(w.z, cp[k8 * 4 + 2], s);
            s = fmaf(w.w, cp[k8 * 4 + 3], s);
        }
        res[jj] = s;
    }
    ((float4*)UH)[(b * 8192 + e0) >> 2] = make_float4(res[0], res[1], res[2], res[3]);
}

// ---------------------------------------------------------------------------
// K8b: 3-iter aspect routing on LDS-resident UH. grid 4, 256 thr. [proven]
__global__ void k_route(const float* __restrict__ UH, float* __restrict__ VA)
{
    const int b = blockIdx.x;
    const int t = threadIdx.x;
    __shared__ float uh[8192], ba[256], cc[256], sbuf[512], msc[32];
#pragma unroll
    for (int i = 0; i < 8; ++i)
        ((float4*)uh)[i * 256 + t] = ((const float4*)UH)[b * 2048 + i * 256 + t];
    ba[t] = 0.f;
    __syncthreads();
    for (int it = 0; it < 3; ++it) {
        if (t < 16) {
            float mx = -1e30f;
            for (int j = 0; j < 16; ++j) mx = fmaxf(mx, ba[t * 16 + j]);
            float sum = 0.f;
            for (int j = 0; j < 16; ++j) { cc[t * 16 + j] = expf(ba[t * 16 + j] - mx); sum += cc[t * 16 + j]; }
            const float inv = 1.f / sum;
            for (int j = 0; j < 16; ++j) cc[t * 16 + j] *= inv;
        }
        __syncthreads();
        for (int h = 0; h < 2; ++h) {
            const int e = h * 256 + t;
            const int j = e >> 5;
            float s = 0.f;
            for (int i = 0; i < 16; ++i) s = fmaf(cc[i * 16 + j], uh[i * 512 + e], s);
            sbuf[e] = s;
        }
        __syncthreads();
        if (t < 32) {
            float mg = 0.f;
            for (int j = 0; j < 16; ++j) { const float x = sbuf[j * 32 + t]; mg = fmaf(x, x, mg); }
            msc[t] = sqrtf(mg) / (1.f + mg);
        }
        __syncthreads();
        for (int h = 0; h < 2; ++h) {
            const int e = h * 256 + t;
            sbuf[e] *= msc[e & 31];
        }
        __syncthreads();
        if (it < 2) {
            const int i = t >> 4, j = t & 15;
            float s = 0.f;
            for (int u = 0; u < 32; ++u) s = fmaf(uh[i * 512 + j * 32 + u], sbuf[j * 32 + u], s);
            ba[t] += s;
            __syncthreads();
        }
    }
    VA[b * 512 + t] = sbuf[t];
    VA[b * 512 + 256 + t] = sbuf[256 + t];
}

// ---------------------------------------------------------------------------
// K9: broadcast VA to all 512 rows per example  [proven]
__global__ void k_out(const float* __restrict__ VA, float* __restrict__ out)
{
    const int idx = blockIdx.x * 256 + threadIdx.x;
    const int b = idx >> 16;
    const int jv4 = idx & 127;
    ((float4*)out)[idx] = ((const float4*)VA)[b * 128 + jv4];
}

// ---------------------------------------------------------------------------
extern "C" void kernel_launch(void* const* d_in, const int* in_sizes, int n_in,
                              void* d_out, int out_size, void* d_ws, size_t ws_size,
                              hipStream_t stream)
{
    const float* X   = (const float*)d_in[0];
    // d_in[1] = hidden — provably unused (softmax shift-invariance kills it)
    const float* Wp  = (const float*)d_in[2];
    const float* bp  = (const float*)d_in[3];
    const float* Wg  = (const float*)d_in[4];
    const float* Wa  = (const float*)d_in[5];
    const float* Wsp = (const float*)d_in[6];
    float* out = (float*)d_out;
    float* ws = (float*)d_ws;

    float* U    = ws + OFF_U;
    float* S    = ws + OFF_S;     // also Upart[4] before k_reduceU
    float* SS   = ws + OFF_SS;
    float* Bg   = ws + OFF_BG;
    float* G    = ws + OFF_G;
    float* VA   = ws + OFF_VA;
    float* MSQ0 = ws + OFF_MSQ0;
    float* MSQ1 = ws + OFF_MSQ1;
    float* UH   = ws + OFF_UH;

    // zero SS(16)+Bg(2048)+G(2048)+VA(2048)+MSQ0(131072)+MSQ1(131072) — contiguous
    hipMemsetAsync(SS, 0, 268304 * sizeof(float), stream);

    k_primary_part<<<dim3(2, 16, 16), 256, 0, stream>>>(X, Wp, S);
    k_reduceU<<<128, 256, 0, stream>>>(S, bp, U, SS);

    // it 0
    k_smatmul<<<dim3(16, 8, 4), 256, 0, stream>>>(U, SS, Bg, Wg, S, MSQ0);
    k_tbu<<<dim3(8, 16, 4), 256, 0, stream>>>(U, SS, S, MSQ0, Wg, Bg);
    // it 1
    k_smatmul<<<dim3(16, 8, 4), 256, 0, stream>>>(U, SS, Bg, Wg, S, MSQ1);
    k_tbu<<<dim3(8, 16, 4), 256, 0, stream>>>(U, SS, S, MSQ1, Wg, Bg);
    // it 2
    k_smatmul<<<dim3(16, 8, 4), 256, 0, stream>>>(U, SS, Bg, Wg, S, nullptr);
    k_maggmean<<<dim3(32, 4), 256, 0, stream>>>(S, G);

    k_uhat<<<dim3(8, 4), 256, 0, stream>>>(G, Wa, Wsp, UH);
    k_route<<<4, 256, 0, stream>>>(UH, VA);
    k_out<<<1024, 256, 0, stream>>>(VA, out);
}

// Round 4
// 227.332 us; speedup vs baseline: 4.0065x; 1.0540x over previous
//
#include <hip/hip_runtime.h>
#include <math.h>

// Problem constants: B=4, GL=4, GF=128, N=1024, CS=32, CN=16, NA=16, S=512
//
// Flat views (fp32, per b):
//  X  : [512 k][1024 n]
//  U  : [128 c][1024 n] ; P2 view: [1024 m][128 q], q=k*32+i, scale sc[l], l=m>>8
//  S  : [1024 m][512 ju]  (UNsquashed; MS holds squash scales)   ju=j*32+u
//  MS : [1024 m][32 u]    squash scale per (m,u)
//  UH : [8192]            u_hat for aspect routing, e = i*512 + j*32 + u

static constexpr int OFF_U  = 0;          // 524288
static constexpr int OFF_S  = 524288;     // 2097152 (also Upart[4][524288])
static constexpr int OFF_SS = 2621440;    // 16
static constexpr int OFF_BG = 2621456;    // 2048
static constexpr int OFF_G  = 2623504;    // 2048
static constexpr int OFF_VA = 2625552;    // 2048
static constexpr int OFF_MS = 2627600;    // 131072
static constexpr int OFF_UH = 2758672;    // 32768

// ---------------------------------------------------------------------------
// K1a: partial U over K-window of 128: Upart[ks] = Wp[:, ks*128:+128] @ X[ks*128:+128, :]
// grid (2 ct, 16 nt, 16 z: b=z>>2, ks=z&3), 256 thr, 4c x 4n outputs each.  [proven]
__global__ void k_primary_part(const float* __restrict__ X, const float* __restrict__ Wp,
                               float* __restrict__ Upart)
{
    __shared__ float Wt[128 * 68];
    const int ct = blockIdx.x, nt = blockIdx.y;
    const int b = blockIdx.z >> 2, ks = blockIdx.z & 3;
    const int t = threadIdx.x;
    const int tn = t & 15, tc = t >> 4;
    const int c0 = ct * 64, n0 = nt * 64;
#pragma unroll
    for (int i = 0; i < 8; ++i) {
        const int idx = t + i * 256;
        const int c = idx >> 5, k4 = idx & 31;
        const float4 wv = *(const float4*)&Wp[(size_t)(c0 + c) * 512 + ks * 128 + k4 * 4];
        Wt[(k4 * 4 + 0) * 68 + c] = wv.x;
        Wt[(k4 * 4 + 1) * 68 + c] = wv.y;
        Wt[(k4 * 4 + 2) * 68 + c] = wv.z;
        Wt[(k4 * 4 + 3) * 68 + c] = wv.w;
    }
    __syncthreads();
    float acc[4][4] = {};
    const float* Xp = X + (size_t)b * 524288 + (size_t)(ks * 128) * 1024 + n0 + tn * 4;
#pragma unroll 4
    for (int k = 0; k < 128; ++k) {
        const float4 xv = *(const float4*)(Xp + (size_t)k * 1024);
        const float4 wv = *(const float4*)&Wt[k * 68 + tc * 4];
        const float w[4] = {wv.x, wv.y, wv.z, wv.w};
        const float x[4] = {xv.x, xv.y, xv.z, xv.w};
#pragma unroll
        for (int ci = 0; ci < 4; ++ci)
#pragma unroll
            for (int ni = 0; ni < 4; ++ni)
                acc[ci][ni] = fmaf(w[ci], x[ni], acc[ci][ni]);
    }
    float* up = Upart + (size_t)ks * 524288 + (size_t)b * 131072;
#pragma unroll
    for (int ci = 0; ci < 4; ++ci)
        *(float4*)&up[(size_t)(c0 + tc * 4 + ci) * 1024 + n0 + tn * 4] =
            make_float4(acc[ci][0], acc[ci][1], acc[ci][2], acc[ci][3]);
}

// ---------------------------------------------------------------------------
// K1b: U = sum_ks Upart[ks] + bp, and SS[b][l] = sum of squares. grid 128.  [proven]
__global__ void k_reduceU(const float* __restrict__ Upart, const float* __restrict__ bp,
                          float* __restrict__ U, float* __restrict__ SS)
{
    __shared__ float red[256];
    const int blk = blockIdx.x, t = threadIdx.x;
    const int b = blk >> 5, cg = blk & 31;
    float ssq = 0.f;
#pragma unroll
    for (int i = 0; i < 4; ++i) {
        const int c = cg * 4 + i;
        const int f4 = b * 32768 + c * 256 + t;
        float4 s = ((const float4*)Upart)[f4];
#pragma unroll
        for (int ks = 1; ks < 4; ++ks) {
            const float4 p = ((const float4*)Upart)[ks * 131072 + f4];
            s.x += p.x; s.y += p.y; s.z += p.z; s.w += p.w;
        }
        const float bv = bp[c];
        s.x += bv; s.y += bv; s.z += bv; s.w += bv;
        ssq = fmaf(s.x, s.x, ssq); ssq = fmaf(s.y, s.y, ssq);
        ssq = fmaf(s.z, s.z, ssq); ssq = fmaf(s.w, s.w, ssq);
        ((float4*)U)[f4] = s;
    }
    red[t] = ssq;
    __syncthreads();
    for (int s = 128; s > 0; s >>= 1) {
        if (t < s) red[t] += red[t + s];
        __syncthreads();
    }
    if (t == 0) atomicAdd(&SS[b * 4 + (cg >> 3)], red[0]);
}

// ---------------------------------------------------------------------------
// K4 v3: S[b][m][ju] = sum_q (U[m][q]*sc) * (cls[i][j]*Wg[i][j][u][k])
// grid (16 mt, 8 jt, 4 b), 64x64 tiles, K=128 in 2 chunks. Staging and FMA
// order over q IDENTICAL to the proven kernel -> S bitwise unchanged.
// CHANGES vs proven (LDS-issue fix):
//  - pad 65 -> 68 floats (272 B rows, 16B-aligned) so b128 LDS reads are legal
//  - inner loop q-chunked x4: explicit float4 LDS reads (8x ds_read_b128 per
//    4q instead of 32x ds_read_b32) -> ~2x less LDS-issue time
//  - thread's j-columns SPREAD (tj + 16*jj, not tj*4+jj): Ct's 16 distinct
//    row addresses land on banks 4*tj mod 32 -> 2-way (free); contiguous
//    mapping would be 8-way. Pt's 4 tm-addresses: 2-way (free).
//  - stores become 16 scalar dwords/thread (64B-coalesced per 16 lanes)
__global__ void k_smatmul(const float* __restrict__ U, const float* __restrict__ SS,
                          const float* __restrict__ Bg, const float* __restrict__ Wg,
                          float* __restrict__ S)
{
    __shared__ __align__(16) float Pt[64 * 68];
    __shared__ __align__(16) float Ct[64 * 68];
    __shared__ float cls[512];
    const int mt = blockIdx.x, jt = blockIdx.y, b = blockIdx.z;
    const int t = threadIdx.x;
    const int tj = t & 15, tm = t >> 4;
    if (t < 32) {
        float vals[16];
        float mx = -1e30f;
        for (int j = 0; j < 16; ++j) { vals[j] = Bg[b * 512 + t * 16 + j]; mx = fmaxf(mx, vals[j]); }
        float sum = 0.f;
        for (int j = 0; j < 16; ++j) { vals[j] = expf(vals[j] - mx); sum += vals[j]; }
        const float inv = 1.f / sum;
        for (int j = 0; j < 16; ++j) cls[t * 16 + j] = vals[j] * inv;
    }
    const float ss = SS[b * 4 + (mt >> 2)];
    const float sc = sqrtf(ss) / (1.f + ss);
    float acc[4][4] = {};
    const float* Ub = U + (size_t)b * 131072 + (size_t)mt * 64 * 128;
    __syncthreads();
    for (int kc = 0; kc < 2; ++kc) {
        // staging: identical global access pattern to the proven kernel
        for (int x = t; x < 64 * 64; x += 256) {
            const int r = x >> 6, cq = x & 63;
            Pt[r * 68 + cq] = Ub[r * 128 + kc * 64 + cq] * sc;
            const int q = kc * 64 + cq;
            const int i = q & 31, kk = q >> 5;
            const int ju = jt * 64 + r;
            const int j = ju >> 5, u = ju & 31;
            Ct[r * 68 + cq] = cls[i * 16 + j] * Wg[((i * 16 + j) * 32 + u) * 4 + kk];
        }
        __syncthreads();
#pragma unroll 4
        for (int q0 = 0; q0 < 64; q0 += 4) {
            float4 pa[4], cb[4];
#pragma unroll
            for (int mm = 0; mm < 4; ++mm)
                pa[mm] = *(const float4*)&Pt[(tm * 4 + mm) * 68 + q0];
#pragma unroll
            for (int jj = 0; jj < 4; ++jj)
                cb[jj] = *(const float4*)&Ct[(tj + 16 * jj) * 68 + q0];
#pragma unroll
            for (int mm = 0; mm < 4; ++mm) {
#pragma unroll
                for (int jj = 0; jj < 4; ++jj) {
                    acc[mm][jj] = fmaf(pa[mm].x, cb[jj].x, acc[mm][jj]);
                    acc[mm][jj] = fmaf(pa[mm].y, cb[jj].y, acc[mm][jj]);
                    acc[mm][jj] = fmaf(pa[mm].z, cb[jj].z, acc[mm][jj]);
                    acc[mm][jj] = fmaf(pa[mm].w, cb[jj].w, acc[mm][jj]);
                }
            }
        }
        __syncthreads();
    }
    // store: thread owns m rows mt*64+tm*4+mm, columns j0 + jj*16 + tj
#pragma unroll
    for (int mm = 0; mm < 4; ++mm) {
        float* Sp = S + (size_t)b * 524288 + (size_t)(mt * 64 + tm * 4 + mm) * 512
                      + jt * 64 + tj;
#pragma unroll
        for (int jj = 0; jj < 4; ++jj)
            Sp[jj * 16] = acc[mm][jj];
    }
}

// ---------------------------------------------------------------------------
// K5: MS[b][m][u] = squash scale over J of S. grid (128, 4 b).  [proven, restored]
__global__ void k_mag(const float* __restrict__ S, float* __restrict__ MS)
{
    const int t = threadIdx.x;
    const int u = t & 31, ml = t >> 5;
    const int m = blockIdx.x * 8 + ml;
    const int b = blockIdx.y;
    const float* row = S + (size_t)b * 524288 + (size_t)m * 512;
    float mag = 0.f;
#pragma unroll
    for (int j = 0; j < 16; ++j) { const float v = row[j * 32 + u]; mag = fmaf(v, v, mag); }
    MS[b * 32768 + m * 32 + u] = sqrtf(mag) / (1.f + mag);
}

// ---------------------------------------------------------------------------
// K5b (last iter): mag + mean fused: G[b][jv] = (1/1024) sum_m S*msc. [proven]
__global__ void k_maggmean(const float* __restrict__ S, float* __restrict__ G)
{
    __shared__ float gacc[512];
    const int t = threadIdx.x;
    gacc[t] = 0.f; gacc[t + 256] = 0.f;
    const int u = t & 31, mlg = t >> 5;
    const int b = blockIdx.y;
    const int m0 = blockIdx.x * 32 + mlg * 4;
    float preg[16];
#pragma unroll
    for (int j = 0; j < 16; ++j) preg[j] = 0.f;
    __syncthreads();
#pragma unroll
    for (int mi = 0; mi < 4; ++mi) {
        const float* row = S + (size_t)b * 524288 + (size_t)(m0 + mi) * 512;
        float sv[16];
        float mag = 0.f;
#pragma unroll
        for (int j = 0; j < 16; ++j) { sv[j] = row[j * 32 + u]; mag = fmaf(sv[j], sv[j], mag); }
        const float msc = sqrtf(mag) / (1.f + mag);
#pragma unroll
        for (int j = 0; j < 16; ++j) preg[j] = fmaf(sv[j], msc, preg[j]);
    }
#pragma unroll
    for (int j = 0; j < 16; ++j) atomicAdd(&gacc[j * 32 + u], preg[j]);
    __syncthreads();
    atomicAdd(&G[b * 512 + t], gacc[t] * (1.f / 1024.f));
    atomicAdd(&G[b * 512 + 256 + t], gacc[t + 256] * (1.f / 1024.f));
}

// ---------------------------------------------------------------------------
// K6: b-update, kt merged. grid (8 jt, 16 mc, 4 b), 256 thr.  [proven, restored
// to MS-reading form]
__global__ void k_tbu(const float* __restrict__ U, const float* __restrict__ SS,
                      const float* __restrict__ S, const float* __restrict__ MS,
                      const float* __restrict__ Wg, float* __restrict__ Bg)
{
    __shared__ float Ps[64 * 132];   // [m][q], pad 132
    __shared__ float Vs[64 * 68];    // [m][jv], pad 68
    __shared__ float bup[64];        // [i][j_loc]
    const int jt = blockIdx.x, mc = blockIdx.y, b = blockIdx.z;
    const int t = threadIdx.x;
    const int tq = t & 31, tjv = t >> 5;
    const int m0 = mc * 64;
    if (t < 64) bup[t] = 0.f;
    const float ss = SS[b * 4 + (mc >> 2)];
    const float sc = sqrtf(ss) / (1.f + ss);
#pragma unroll
    for (int i = 0; i < 8; ++i) {
        const int f4 = t + i * 256;
        const int r = f4 >> 5, q4 = f4 & 31;
        float4 v = *(const float4*)&U[(size_t)b * 131072 + (size_t)(m0 + r) * 128 + q4 * 4];
        v.x *= sc; v.y *= sc; v.z *= sc; v.w *= sc;
        *(float4*)&Ps[r * 132 + q4 * 4] = v;
    }
#pragma unroll
    for (int i = 0; i < 4; ++i) {
        const int f4 = t + i * 256;
        const int r = f4 >> 4, c4 = f4 & 15;
        const int m = m0 + r;
        float4 v = *(const float4*)&S[(size_t)b * 524288 + (size_t)m * 512 + jt * 64 + c4 * 4];
        const int ub = (c4 * 4) & 31;
        const float* msp = MS + b * 32768 + m * 32;
        v.x *= msp[ub + 0]; v.y *= msp[ub + 1]; v.z *= msp[ub + 2]; v.w *= msp[ub + 3];
        *(float4*)&Vs[r * 68 + c4 * 4] = v;
    }
    __syncthreads();
    float acc[4][8] = {};
#pragma unroll 2
    for (int m = 0; m < 64; ++m) {
        const float4 p4 = *(const float4*)&Ps[m * 132 + tq * 4];
        const float4 va = *(const float4*)&Vs[m * 68 + tjv * 8];
        const float4 vb = *(const float4*)&Vs[m * 68 + tjv * 8 + 4];
        const float pv[4] = {p4.x, p4.y, p4.z, p4.w};
        const float vv[8] = {va.x, va.y, va.z, va.w, vb.x, vb.y, vb.z, vb.w};
#pragma unroll
        for (int qi = 0; qi < 4; ++qi)
#pragma unroll
            for (int ji = 0; ji < 8; ++ji)
                acc[qi][ji] = fmaf(pv[qi], vv[ji], acc[qi][ji]);
    }
    const int k = tq >> 3;
    const int j_loc = tjv >> 2;
    const int j = jt * 2 + j_loc;
    const int u0 = (tjv & 3) * 8;
#pragma unroll
    for (int qi = 0; qi < 4; ++qi) {
        const int i = (tq & 7) * 4 + qi;
        const float* wp = Wg + ((i * 16 + j) * 32) * 4 + k;
        float s = 0.f;
#pragma unroll
        for (int ji = 0; ji < 8; ++ji)
            s = fmaf(wp[(u0 + ji) * 4], acc[qi][ji], s);
        s += __shfl_xor(s, 8);
        s += __shfl_xor(s, 16);
        s += __shfl_xor(s, 32);
        if ((t & 56) == 0) atomicAdd(&bup[i * 2 + j_loc], s);
    }
    __syncthreads();
    if (t < 64) {
        const int ii = t >> 1, jl = t & 1;
        atomicAdd(&Bg[b * 512 + ii * 16 + jt * 2 + jl], bup[t] * (1.f / 1024.f));
    }
}

// ---------------------------------------------------------------------------
// K8a: UH[b][e] = sum_k Ws[e][k] * cond[b][i*32+k]. grid (8 slices, 4 b). [proven]
__global__ void k_uhat(const float* __restrict__ G, const float* __restrict__ Wa,
                       const float* __restrict__ Ws, float* __restrict__ UH)
{
    const int b = blockIdx.y;
    const int t = threadIdx.x;
    __shared__ float g[512], cond[512], score[16], red[16];
    g[t] = G[b * 512 + t];
    g[t + 256] = G[b * 512 + 256 + t];
    __syncthreads();
    if (t < 16) {
        float s = 0.f;
        for (int u = 0; u < 32; ++u) s = fmaf(g[t * 32 + u], Wa[u], s);
        red[t] = s;
    }
    __syncthreads();
    if (t == 0) {
        float mx = -1e30f;
        for (int j = 0; j < 16; ++j) mx = fmaxf(mx, red[j]);
        float sum = 0.f;
        for (int j = 0; j < 16; ++j) { score[j] = expf(red[j] - mx); sum += score[j]; }
        const float inv = 1.f / sum;
        for (int j = 0; j < 16; ++j) score[j] *= inv;
    }
    __syncthreads();
    cond[t] = g[t] * score[t >> 5];
    cond[t + 256] = g[t + 256] * score[(t + 256) >> 5];
    __syncthreads();
    const int e0 = blockIdx.x * 1024 + t * 4;
    const int i = e0 >> 9;
    const float* cp = cond + i * 32;
    const float* wp = Ws + (size_t)e0 * 32;
    float res[4];
#pragma unroll
    for (int jj = 0; jj < 4; ++jj) {
        float s = 0.f;
#pragma unroll
        for (int k8 = 0; k8 < 8; ++k8) {
            const float4 w = *(const float4*)(wp + jj * 32 + k8 * 4);
            s = fmaf(w.x, cp[k8 * 4 + 0], s);
            s = fmaf(w.y, cp[k8 * 4 + 1], s);
            s = fmaf(w.z, cp[k8 * 4 + 2], s);
            s = fmaf(w.w, cp[k8 * 4 + 3], s);
        }
        res[jj] = s;
    }
    ((float4*)UH)[(b * 8192 + e0) >> 2] = make_float4(res[0], res[1], res[2], res[3]);
}

// ---------------------------------------------------------------------------
// K8b: 3-iter aspect routing on LDS-resident UH. grid 4, 256 thr. [proven]
__global__ void k_route(const float* __restrict__ UH, float* __restrict__ VA)
{
    const int b = blockIdx.x;
    const int t = threadIdx.x;
    __shared__ float uh[8192], ba[256], cc[256], sbuf[512], msc[32];
#pragma unroll
    for (int i = 0; i < 8; ++i)
        ((float4*)uh)[i * 256 + t] = ((const float4*)UH)[b * 2048 + i * 256 + t];
    ba[t] = 0.f;
    __syncthreads();
    for (int it = 0; it < 3; ++it) {
        if (t < 16) {
            float mx = -1e30f;
            for (int j = 0; j < 16; ++j) mx = fmaxf(mx, ba[t * 16 + j]);
            float sum = 0.f;
            for (int j = 0; j < 16; ++j) { cc[t * 16 + j] = expf(ba[t * 16 + j] - mx); sum += cc[t * 16 + j]; }
            const float inv = 1.f / sum;
            for (int j = 0; j < 16; ++j) cc[t * 16 + j] *= inv;
        }
        __syncthreads();
        for (int h = 0; h < 2; ++h) {
            const int e = h * 256 + t;
            const int j = e >> 5;
            float s = 0.f;
            for (int i = 0; i < 16; ++i) s = fmaf(cc[i * 16 + j], uh[i * 512 + e], s);
            sbuf[e] = s;
        }
        __syncthreads();
        if (t < 32) {
            float mg = 0.f;
            for (int j = 0; j < 16; ++j) { const float x = sbuf[j * 32 + t]; mg = fmaf(x, x, mg); }
            msc[t] = sqrtf(mg) / (1.f + mg);
        }
        __syncthreads();
        for (int h = 0; h < 2; ++h) {
            const int e = h * 256 + t;
            sbuf[e] *= msc[e & 31];
        }
        __syncthreads();
        if (it < 2) {
            const int i = t >> 4, j = t & 15;
            float s = 0.f;
            for (int u = 0; u < 32; ++u) s = fmaf(uh[i * 512 + j * 32 + u], sbuf[j * 32 + u], s);
            ba[t] += s;
            __syncthreads();
        }
    }
    VA[b * 512 + t] = sbuf[t];
    VA[b * 512 + 256 + t] = sbuf[256 + t];
}

// ---------------------------------------------------------------------------
// K9: broadcast VA to all 512 rows per example  [proven]
__global__ void k_out(const float* __restrict__ VA, float* __restrict__ out)
{
    const int idx = blockIdx.x * 256 + threadIdx.x;
    const int b = idx >> 16;
    const int jv4 = idx & 127;
    ((float4*)out)[idx] = ((const float4*)VA)[b * 128 + jv4];
}

// ---------------------------------------------------------------------------
extern "C" void kernel_launch(void* const* d_in, const int* in_sizes, int n_in,
                              void* d_out, int out_size, void* d_ws, size_t ws_size,
                              hipStream_t stream)
{
    const float* X   = (const float*)d_in[0];
    // d_in[1] = hidden — provably unused (softmax shift-invariance kills it)
    const float* Wp  = (const float*)d_in[2];
    const float* bp  = (const float*)d_in[3];
    const float* Wg  = (const float*)d_in[4];
    const float* Wa  = (const float*)d_in[5];
    const float* Wsp = (const float*)d_in[6];
    float* out = (float*)d_out;
    float* ws = (float*)d_ws;

    float* U  = ws + OFF_U;
    float* S  = ws + OFF_S;     // also Upart[4] before k_reduceU
    float* SS = ws + OFF_SS;
    float* Bg = ws + OFF_BG;
    float* G  = ws + OFF_G;
    float* VA = ws + OFF_VA;
    float* MS = ws + OFF_MS;
    float* UH = ws + OFF_UH;

    // zero SS(16) + Bg(2048) + G(2048) — contiguous
    hipMemsetAsync(SS, 0, (16 + 2048 + 2048) * sizeof(float), stream);

    k_primary_part<<<dim3(2, 16, 16), 256, 0, stream>>>(X, Wp, S);
    k_reduceU<<<128, 256, 0, stream>>>(S, bp, U, SS);

    for (int it = 0; it < 3; ++it) {
        k_smatmul<<<dim3(16, 8, 4), 256, 0, stream>>>(U, SS, Bg, Wg, S);
        if (it < 2) {
            k_mag<<<dim3(128, 4), 256, 0, stream>>>(S, MS);
            k_tbu<<<dim3(8, 16, 4), 256, 0, stream>>>(U, SS, S, MS, Wg, Bg);
        } else {
            k_maggmean<<<dim3(32, 4), 256, 0, stream>>>(S, G);
        }
    }

    k_uhat<<<dim3(8, 4), 256, 0, stream>>>(G, Wa, Wsp, UH);
    k_route<<<4, 256, 0, stream>>>(UH, VA);
    k_out<<<1024, 256, 0, stream>>>(VA, out);
}

// Round 5
// 196.434 us; speedup vs baseline: 4.6367x; 1.1573x over previous
//
#include <hip/hip_runtime.h>
#include <math.h>

// Problem constants: B=4, GL=4, GF=128, N=1024, CS=32, CN=16, NA=16, S=512
//
// Flat views (fp32, per b):
//  X   : [512 k][1024 n]
//  U   : [128 c][1024 n] ; P2 view: [1024 m][128 q], q=k*32+i, scale sc[l], l=m>>8
//  S   : [1024 m][512 ju]  (UNsquashed)   ju=j*32+u
//  MS  : [1024 m][32 u]    squash scale per (m,u)
//  UH  : [8192]            u_hat for aspect routing, e = i*512 + j*32 + u
//  WGR : [128 q][32 u][16 j] reordered Wg (cls-independent, built once)

static constexpr int OFF_U   = 0;          // 524288
static constexpr int OFF_S   = 524288;     // 2097152 (also Upart[4][524288])
static constexpr int OFF_SS  = 2621440;    // 16
static constexpr int OFF_BG  = 2621456;    // 2048
static constexpr int OFF_G   = 2623504;    // 2048
static constexpr int OFF_VA  = 2625552;    // 2048
static constexpr int OFF_MS  = 2627600;    // 131072
static constexpr int OFF_UH  = 2758672;    // 32768
static constexpr int OFF_WGR = 2791440;    // 65536 (fits: prior rounds used ws through 2922512)

// ---------------------------------------------------------------------------
// K1a: partial U over K-window of 128 (z<16)  [proven]
//      + z==16: one-time Wg reorder into WGR (32 blocks ride free on this grid)
__global__ void k_primary_part(const float* __restrict__ X, const float* __restrict__ Wp,
                               float* __restrict__ Upart,
                               const float* __restrict__ Wg, float* __restrict__ Wgr)
{
    __shared__ float Wt[128 * 68];
    const int t = threadIdx.x;
    if (blockIdx.z == 16) {
        // Wgr[q*512 + u*16 + j] = Wg[((i*16+j)*32+u)*4 + kk], q = kk*32+i
        const int blk = blockIdx.x * 16 + blockIdx.y;       // 0..31
#pragma unroll
        for (int r = 0; r < 8; ++r) {
            const int e = blk * 2048 + r * 256 + t;         // 0..65535
            const int q = e >> 9, rem = e & 511;
            const int u = rem >> 4, j = rem & 15;
            const int i = q & 31, kk = q >> 5;
            Wgr[e] = Wg[((i * 16 + j) * 32 + u) * 4 + kk];
        }
        return;
    }
    const int ct = blockIdx.x, nt = blockIdx.y;
    const int b = blockIdx.z >> 2, ks = blockIdx.z & 3;
    const int tn = t & 15, tc = t >> 4;
    const int c0 = ct * 64, n0 = nt * 64;
#pragma unroll
    for (int i = 0; i < 8; ++i) {
        const int idx = t + i * 256;
        const int c = idx >> 5, k4 = idx & 31;
        const float4 wv = *(const float4*)&Wp[(size_t)(c0 + c) * 512 + ks * 128 + k4 * 4];
        Wt[(k4 * 4 + 0) * 68 + c] = wv.x;
        Wt[(k4 * 4 + 1) * 68 + c] = wv.y;
        Wt[(k4 * 4 + 2) * 68 + c] = wv.z;
        Wt[(k4 * 4 + 3) * 68 + c] = wv.w;
    }
    __syncthreads();
    float acc[4][4] = {};
    const float* Xp = X + (size_t)b * 524288 + (size_t)(ks * 128) * 1024 + n0 + tn * 4;
#pragma unroll 4
    for (int k = 0; k < 128; ++k) {
        const float4 xv = *(const float4*)(Xp + (size_t)k * 1024);
        const float4 wv = *(const float4*)&Wt[k * 68 + tc * 4];
        const float w[4] = {wv.x, wv.y, wv.z, wv.w};
        const float x[4] = {xv.x, xv.y, xv.z, xv.w};
#pragma unroll
        for (int ci = 0; ci < 4; ++ci)
#pragma unroll
            for (int ni = 0; ni < 4; ++ni)
                acc[ci][ni] = fmaf(w[ci], x[ni], acc[ci][ni]);
    }
    float* up = Upart + (size_t)ks * 524288 + (size_t)b * 131072;
#pragma unroll
    for (int ci = 0; ci < 4; ++ci)
        *(float4*)&up[(size_t)(c0 + tc * 4 + ci) * 1024 + n0 + tn * 4] =
            make_float4(acc[ci][0], acc[ci][1], acc[ci][2], acc[ci][3]);
}

// ---------------------------------------------------------------------------
// K1b: U = sum_ks Upart[ks] + bp, and SS[b][l] = sum of squares. grid 128.  [proven]
__global__ void k_reduceU(const float* __restrict__ Upart, const float* __restrict__ bp,
                          float* __restrict__ U, float* __restrict__ SS)
{
    __shared__ float red[256];
    const int blk = blockIdx.x, t = threadIdx.x;
    const int b = blk >> 5, cg = blk & 31;
    float ssq = 0.f;
#pragma unroll
    for (int i = 0; i < 4; ++i) {
        const int c = cg * 4 + i;
        const int f4 = b * 32768 + c * 256 + t;
        float4 s = ((const float4*)Upart)[f4];
#pragma unroll
        for (int ks = 1; ks < 4; ++ks) {
            const float4 p = ((const float4*)Upart)[ks * 131072 + f4];
            s.x += p.x; s.y += p.y; s.z += p.z; s.w += p.w;
        }
        const float bv = bp[c];
        s.x += bv; s.y += bv; s.z += bv; s.w += bv;
        ssq = fmaf(s.x, s.x, ssq); ssq = fmaf(s.y, s.y, ssq);
        ssq = fmaf(s.z, s.z, ssq); ssq = fmaf(s.w, s.w, ssq);
        ((float4*)U)[f4] = s;
    }
    red[t] = ssq;
    __syncthreads();
    for (int s = 128; s > 0; s >>= 1) {
        if (t < s) red[t] += red[t + s];
        __syncthreads();
    }
    if (t == 0) atomicAdd(&SS[b * 4 + (cg >> 3)], red[0]);
}

// ---------------------------------------------------------------------------
// K4 v4 "smatmulM": S = (P2*sc) @ (cls o Wg), u-sliced grid so each block owns
// ALL 16 j for its u-range -> MS (squash scale over j) computed IN-BLOCK.
// grid (16 mt, 4 us, 4 b) = 256 blocks, 256 thr, thread tile 4m x 8j.
// - Replaces k_mag (x2) and k_maggmean (G accumulated in last call's epilogue).
// - Per-output LDS bytes: 48B/32 outputs = 1.5 (old: 32B/16 = 2.0) -> less LDS-BW.
// - Ct staged from WGR (coalesced) instead of scattered Wg.
// - FMA order over q (0..127 asc) identical to proven kernel -> S bitwise same.
// Thread: tm = t>>4 (m-group), uu = t&7 (u within slice), jh = (t>>3)&1 (j half).
// Ct layout: c = u2*16 + j, stored at cpad = c + 4*(c>>4) (2-way banks on reads).
__global__ __launch_bounds__(256) void k_smatmulM(
    const float* __restrict__ U, const float* __restrict__ SS,
    const float* __restrict__ Bg, const float* __restrict__ Wgr,
    float* __restrict__ S, float* __restrict__ MS, float* __restrict__ G)
{
    __shared__ __align__(16) float Pt[64 * 68];    // [qL][m]
    __shared__ __align__(16) float Ct[64 * 160];   // [qL][cpad]
    __shared__ float cls[512];
    __shared__ float gacc[128];
    const int mt = blockIdx.x, us = blockIdx.y, b = blockIdx.z;
    const int t = threadIdx.x;
    const int tm = t >> 4;
    const int uu = t & 7, jh = (t >> 3) & 1;
    const int m0 = mt * 64;

    if (t < 32) {
        float vals[16];
        float mx = -1e30f;
        for (int j = 0; j < 16; ++j) { vals[j] = Bg[b * 512 + t * 16 + j]; mx = fmaxf(mx, vals[j]); }
        float sum = 0.f;
        for (int j = 0; j < 16; ++j) { vals[j] = expf(vals[j] - mx); sum += vals[j]; }
        const float inv = 1.f / sum;
        for (int j = 0; j < 16; ++j) cls[t * 16 + j] = vals[j] * inv;
    }
    if (G != nullptr && t < 128) gacc[t] = 0.f;
    const float ss = SS[b * 4 + (mt >> 2)];
    const float sc = sqrtf(ss) / (1.f + ss);
    float acc[4][8] = {};
    const float* Ub = U + (size_t)b * 131072 + (size_t)m0 * 128;
    __syncthreads();

    for (int kc = 0; kc < 2; ++kc) {
        // stage Pt[qL][m] (transposed): coalesced-ish float4 gathers, stride-1 LDS writes
#pragma unroll
        for (int it = 0; it < 4; ++it) {
            const int x = t + it * 256;           // 0..1023
            const int m = x & 63, q4 = x >> 6;    // q4 0..15
            const float4 v = *(const float4*)&Ub[(size_t)m * 128 + kc * 64 + q4 * 4];
            Pt[(q4 * 4 + 0) * 68 + m] = v.x * sc;
            Pt[(q4 * 4 + 1) * 68 + m] = v.y * sc;
            Pt[(q4 * 4 + 2) * 68 + m] = v.z * sc;
            Pt[(q4 * 4 + 3) * 68 + m] = v.w * sc;
        }
        // stage Ct[qL][cpad]: WGR float4 loads fully coalesced
#pragma unroll
        for (int it = 0; it < 8; ++it) {
            const int x = t + it * 256;           // 0..2047
            const int c4 = (x & 31) * 4, qL = x >> 5;
            const int q = kc * 64 + qL;
            const int i = q & 31;
            const int j0 = c4 & 15;
            const float4 w = *(const float4*)&Wgr[(size_t)q * 512 + us * 128 + c4];
            const int cp = qL * 160 + c4 + ((c4 >> 4) << 2);
            Ct[cp + 0] = cls[i * 16 + j0 + 0] * w.x;
            Ct[cp + 1] = cls[i * 16 + j0 + 1] * w.y;
            Ct[cp + 2] = cls[i * 16 + j0 + 2] * w.z;
            Ct[cp + 3] = cls[i * 16 + j0 + 3] * w.w;
        }
        __syncthreads();
        const int cbase = uu * 20 + jh * 8;       // cpad of c = uu*16 + jh*8
#pragma unroll 4
        for (int qL = 0; qL < 64; ++qL) {
            const float4 p4 = *(const float4*)&Pt[qL * 68 + tm * 4];
            const float4 ca = *(const float4*)&Ct[qL * 160 + cbase];
            const float4 cb = *(const float4*)&Ct[qL * 160 + cbase + 4];
            const float pm[4] = {p4.x, p4.y, p4.z, p4.w};
            const float cj[8] = {ca.x, ca.y, ca.z, ca.w, cb.x, cb.y, cb.z, cb.w};
#pragma unroll
            for (int mm = 0; mm < 4; ++mm)
#pragma unroll
                for (int jj = 0; jj < 8; ++jj)
                    acc[mm][jj] = fmaf(pm[mm], cj[jj], acc[mm][jj]);
        }
        __syncthreads();
    }

    // store S: ju = (jh*8+jj)*32 + us*8 + uu
#pragma unroll
    for (int mm = 0; mm < 4; ++mm) {
        float* Sp = S + (size_t)b * 524288 + (size_t)(m0 + tm * 4 + mm) * 512 + us * 8 + uu;
#pragma unroll
        for (int jj = 0; jj < 8; ++jj)
            Sp[(jh * 8 + jj) * 32] = acc[mm][jj];
    }

    if (G == nullptr) {
        // MS[m][u] = squash scale from full-j sum of squares (jh pair via shfl)
#pragma unroll
        for (int mm = 0; mm < 4; ++mm) {
            float msq = 0.f;
#pragma unroll
            for (int jj = 0; jj < 8; ++jj) msq = fmaf(acc[mm][jj], acc[mm][jj], msq);
            msq += __shfl_xor(msq, 8);
            if (jh == 0)
                MS[b * 32768 + (m0 + tm * 4 + mm) * 32 + us * 8 + uu] =
                    sqrtf(msq) / (1.f + msq);
        }
    } else {
        // last iter: G[b][ju] += (1/1024) sum_m S*msc
        float part[8];
#pragma unroll
        for (int jj = 0; jj < 8; ++jj) part[jj] = 0.f;
#pragma unroll
        for (int mm = 0; mm < 4; ++mm) {
            float msq = 0.f;
#pragma unroll
            for (int jj = 0; jj < 8; ++jj) msq = fmaf(acc[mm][jj], acc[mm][jj], msq);
            msq += __shfl_xor(msq, 8);
            const float msc = sqrtf(msq) / (1.f + msq);
#pragma unroll
            for (int jj = 0; jj < 8; ++jj) part[jj] = fmaf(acc[mm][jj], msc, part[jj]);
        }
#pragma unroll
        for (int jj = 0; jj < 8; ++jj)
            atomicAdd(&gacc[(jh * 8 + jj) * 8 + uu], part[jj]);
        __syncthreads();
        if (t < 128) {
            const int j = t >> 3, u2 = t & 7;
            atomicAdd(&G[b * 512 + j * 32 + us * 8 + u2], gacc[t] * (1.f / 1024.f));
        }
    }
}

// ---------------------------------------------------------------------------
// K6: b-update, kt merged. grid (8 jt, 16 mc, 4 b), 256 thr.  [proven]
__global__ void k_tbu(const float* __restrict__ U, const float* __restrict__ SS,
                      const float* __restrict__ S, const float* __restrict__ MS,
                      const float* __restrict__ Wg, float* __restrict__ Bg)
{
    __shared__ float Ps[64 * 132];   // [m][q], pad 132
    __shared__ float Vs[64 * 68];    // [m][jv], pad 68
    __shared__ float bup[64];        // [i][j_loc]
    const int jt = blockIdx.x, mc = blockIdx.y, b = blockIdx.z;
    const int t = threadIdx.x;
    const int tq = t & 31, tjv = t >> 5;
    const int m0 = mc * 64;
    if (t < 64) bup[t] = 0.f;
    const float ss = SS[b * 4 + (mc >> 2)];
    const float sc = sqrtf(ss) / (1.f + ss);
#pragma unroll
    for (int i = 0; i < 8; ++i) {
        const int f4 = t + i * 256;
        const int r = f4 >> 5, q4 = f4 & 31;
        float4 v = *(const float4*)&U[(size_t)b * 131072 + (size_t)(m0 + r) * 128 + q4 * 4];
        v.x *= sc; v.y *= sc; v.z *= sc; v.w *= sc;
        *(float4*)&Ps[r * 132 + q4 * 4] = v;
    }
#pragma unroll
    for (int i = 0; i < 4; ++i) {
        const int f4 = t + i * 256;
        const int r = f4 >> 4, c4 = f4 & 15;
        const int m = m0 + r;
        float4 v = *(const float4*)&S[(size_t)b * 524288 + (size_t)m * 512 + jt * 64 + c4 * 4];
        const int ub = (c4 * 4) & 31;
        const float* msp = MS + b * 32768 + m * 32;
        v.x *= msp[ub + 0]; v.y *= msp[ub + 1]; v.z *= msp[ub + 2]; v.w *= msp[ub + 3];
        *(float4*)&Vs[r * 68 + c4 * 4] = v;
    }
    __syncthreads();
    float acc[4][8] = {};
#pragma unroll 2
    for (int m = 0; m < 64; ++m) {
        const float4 p4 = *(const float4*)&Ps[m * 132 + tq * 4];
        const float4 va = *(const float4*)&Vs[m * 68 + tjv * 8];
        const float4 vb = *(const float4*)&Vs[m * 68 + tjv * 8 + 4];
        const float pv[4] = {p4.x, p4.y, p4.z, p4.w};
        const float vv[8] = {va.x, va.y, va.z, va.w, vb.x, vb.y, vb.z, vb.w};
#pragma unroll
        for (int qi = 0; qi < 4; ++qi)
#pragma unroll
            for (int ji = 0; ji < 8; ++ji)
                acc[qi][ji] = fmaf(pv[qi], vv[ji], acc[qi][ji]);
    }
    const int k = tq >> 3;
    const int j_loc = tjv >> 2;
    const int j = jt * 2 + j_loc;
    const int u0 = (tjv & 3) * 8;
#pragma unroll
    for (int qi = 0; qi < 4; ++qi) {
        const int i = (tq & 7) * 4 + qi;
        const float* wp = Wg + ((i * 16 + j) * 32) * 4 + k;
        float s = 0.f;
#pragma unroll
        for (int ji = 0; ji < 8; ++ji)
            s = fmaf(wp[(u0 + ji) * 4], acc[qi][ji], s);
        s += __shfl_xor(s, 8);
        s += __shfl_xor(s, 16);
        s += __shfl_xor(s, 32);
        if ((t & 56) == 0) atomicAdd(&bup[i * 2 + j_loc], s);
    }
    __syncthreads();
    if (t < 64) {
        const int ii = t >> 1, jl = t & 1;
        atomicAdd(&Bg[b * 512 + ii * 16 + jt * 2 + jl], bup[t] * (1.f / 1024.f));
    }
}

// ---------------------------------------------------------------------------
// K8a: UH[b][e] = sum_k Ws[e][k] * cond[b][i*32+k]. grid (8 slices, 4 b). [proven]
__global__ void k_uhat(const float* __restrict__ G, const float* __restrict__ Wa,
                       const float* __restrict__ Ws, float* __restrict__ UH)
{
    const int b = blockIdx.y;
    const int t = threadIdx.x;
    __shared__ float g[512], cond[512], score[16], red[16];
    g[t] = G[b * 512 + t];
    g[t + 256] = G[b * 512 + 256 + t];
    __syncthreads();
    if (t < 16) {
        float s = 0.f;
        for (int u = 0; u < 32; ++u) s = fmaf(g[t * 32 + u], Wa[u], s);
        red[t] = s;
    }
    __syncthreads();
    if (t == 0) {
        float mx = -1e30f;
        for (int j = 0; j < 16; ++j) mx = fmaxf(mx, red[j]);
        float sum = 0.f;
        for (int j = 0; j < 16; ++j) { score[j] = expf(red[j] - mx); sum += score[j]; }
        const float inv = 1.f / sum;
        for (int j = 0; j < 16; ++j) score[j] *= inv;
    }
    __syncthreads();
    cond[t] = g[t] * score[t >> 5];
    cond[t + 256] = g[t + 256] * score[(t + 256) >> 5];
    __syncthreads();
    const int e0 = blockIdx.x * 1024 + t * 4;
    const int i = e0 >> 9;
    const float* cp = cond + i * 32;
    const float* wp = Ws + (size_t)e0 * 32;
    float res[4];
#pragma unroll
    for (int jj = 0; jj < 4; ++jj) {
        float s = 0.f;
#pragma unroll
        for (int k8 = 0; k8 < 8; ++k8) {
            const float4 w = *(const float4*)(wp + jj * 32 + k8 * 4);
            s = fmaf(w.x, cp[k8 * 4 + 0], s);
            s = fmaf(w.y, cp[k8 * 4 + 1], s);
            s = fmaf(w.z, cp[k8 * 4 + 2], s);
            s = fmaf(w.w, cp[k8 * 4 + 3], s);
        }
        res[jj] = s;
    }
    ((float4*)UH)[(b * 8192 + e0) >> 2] = make_float4(res[0], res[1], res[2], res[3]);
}

// ---------------------------------------------------------------------------
// K8b: 3-iter aspect routing on LDS-resident UH. grid 4, 256 thr. [proven]
__global__ void k_route(const float* __restrict__ UH, float* __restrict__ VA)
{
    const int b = blockIdx.x;
    const int t = threadIdx.x;
    __shared__ float uh[8192], ba[256], cc[256], sbuf[512], msc[32];
#pragma unroll
    for (int i = 0; i < 8; ++i)
        ((float4*)uh)[i * 256 + t] = ((const float4*)UH)[b * 2048 + i * 256 + t];
    ba[t] = 0.f;
    __syncthreads();
    for (int it = 0; it < 3; ++it) {
        if (t < 16) {
            float mx = -1e30f;
            for (int j = 0; j < 16; ++j) mx = fmaxf(mx, ba[t * 16 + j]);
            float sum = 0.f;
            for (int j = 0; j < 16; ++j) { cc[t * 16 + j] = expf(ba[t * 16 + j] - mx); sum += cc[t * 16 + j]; }
            const float inv = 1.f / sum;
            for (int j = 0; j < 16; ++j) cc[t * 16 + j] *= inv;
        }
        __syncthreads();
        for (int h = 0; h < 2; ++h) {
            const int e = h * 256 + t;
            const int j = e >> 5;
            float s = 0.f;
            for (int i = 0; i < 16; ++i) s = fmaf(cc[i * 16 + j], uh[i * 512 + e], s);
            sbuf[e] = s;
        }
        __syncthreads();
        if (t < 32) {
            float mg = 0.f;
            for (int j = 0; j < 16; ++j) { const float x = sbuf[j * 32 + t]; mg = fmaf(x, x, mg); }
            msc[t] = sqrtf(mg) / (1.f + mg);
        }
        __syncthreads();
        for (int h = 0; h < 2; ++h) {
            const int e = h * 256 + t;
            sbuf[e] *= msc[e & 31];
        }
        __syncthreads();
        if (it < 2) {
            const int i = t >> 4, j = t & 15;
            float s = 0.f;
            for (int u = 0; u < 32; ++u) s = fmaf(uh[i * 512 + j * 32 + u], sbuf[j * 32 + u], s);
            ba[t] += s;
            __syncthreads();
        }
    }
    VA[b * 512 + t] = sbuf[t];
    VA[b * 512 + 256 + t] = sbuf[256 + t];
}

// ---------------------------------------------------------------------------
// K9: broadcast VA to all 512 rows per example  [proven]
__global__ void k_out(const float* __restrict__ VA, float* __restrict__ out)
{
    const int idx = blockIdx.x * 256 + threadIdx.x;
    const int b = idx >> 16;
    const int jv4 = idx & 127;
    ((float4*)out)[idx] = ((const float4*)VA)[b * 128 + jv4];
}

// ---------------------------------------------------------------------------
extern "C" void kernel_launch(void* const* d_in, const int* in_sizes, int n_in,
                              void* d_out, int out_size, void* d_ws, size_t ws_size,
                              hipStream_t stream)
{
    const float* X   = (const float*)d_in[0];
    // d_in[1] = hidden — provably unused (softmax shift-invariance kills it)
    const float* Wp  = (const float*)d_in[2];
    const float* bp  = (const float*)d_in[3];
    const float* Wg  = (const float*)d_in[4];
    const float* Wa  = (const float*)d_in[5];
    const float* Wsp = (const float*)d_in[6];
    float* out = (float*)d_out;
    float* ws = (float*)d_ws;

    float* U   = ws + OFF_U;
    float* S   = ws + OFF_S;     // also Upart[4] before k_reduceU
    float* SS  = ws + OFF_SS;
    float* Bg  = ws + OFF_BG;
    float* G   = ws + OFF_G;
    float* VA  = ws + OFF_VA;
    float* MS  = ws + OFF_MS;
    float* UH  = ws + OFF_UH;
    float* Wgr = ws + OFF_WGR;

    // zero SS(16) + Bg(2048) + G(2048) — contiguous
    hipMemsetAsync(SS, 0, (16 + 2048 + 2048) * sizeof(float), stream);

    // primary GEMM partials + (z==16) one-time Wg reorder
    k_primary_part<<<dim3(2, 16, 17), 256, 0, stream>>>(X, Wp, S, Wg, Wgr);
    k_reduceU<<<128, 256, 0, stream>>>(S, bp, U, SS);

    // routing: smatmulM computes S + MS (iters 0,1) or S + G (iter 2)
    k_smatmulM<<<dim3(16, 4, 4), 256, 0, stream>>>(U, SS, Bg, Wgr, S, MS, nullptr);
    k_tbu<<<dim3(8, 16, 4), 256, 0, stream>>>(U, SS, S, MS, Wg, Bg);
    k_smatmulM<<<dim3(16, 4, 4), 256, 0, stream>>>(U, SS, Bg, Wgr, S, MS, nullptr);
    k_tbu<<<dim3(8, 16, 4), 256, 0, stream>>>(U, SS, S, MS, Wg, Bg);
    k_smatmulM<<<dim3(16, 4, 4), 256, 0, stream>>>(U, SS, Bg, Wgr, S, nullptr, G);

    k_uhat<<<dim3(8, 4), 256, 0, stream>>>(G, Wa, Wsp, UH);
    k_route<<<4, 256, 0, stream>>>(UH, VA);
    k_out<<<1024, 256, 0, stream>>>(VA, out);
}